// Round 17
// baseline (223.642 us; speedup 1.0000x reference)
//
#include <hip/hip_runtime.h>
#include <hip/hip_bf16.h>
#include <cstdint>

// Problem constants
constexpr int BB = 64;    // batch
constexpr int TT = 12;    // time
constexpr int NN = 512;   // nodes
constexpr int FF = 64;    // features
constexpr int UU = 64;    // units
constexpr int MAXNZ = 128;

// ---------------------------------------------------------------------------
// Workspace layout (bytes):
//   floats: lhs 0 / rhs 393216f / beT 786432f / evals 1048576f
//   ints:   nnz 20971520 / cidx 20973568 / ccnt 21235712 / colj 21237760
//   xT (B,N,T,F) bf16 : 21516288, 50331648 B
//   KF (8 frags x 64 lanes x 8 bf16) : 71847936, 8192 B
// ---------------------------------------------------------------------------
constexpr size_t OF_LHS   = 0;
constexpr size_t OF_RHS   = 393216;
constexpr size_t OF_BET   = 786432;
constexpr size_t OF_EVALS = 1048576;
constexpr size_t OB_NNZ   = 20971520;
constexpr size_t OB_CIDX  = 20973568;
constexpr size_t OB_CCNT  = 21235712;
constexpr size_t OB_COLJ  = 21237760;
constexpr size_t OB_XT    = 21516288;
constexpr size_t XT_BYTES = (size_t)BB * NN * TT * FF * 2;  // 50331648
constexpr size_t OB_KF    = 71847936;
constexpr size_t KF_BYTES = 8 * 64 * 8 * 2;                 // 8192

typedef __attribute__((ext_vector_type(8))) short bf16x8;   // 8 bf16 = 4 VGPRs
typedef __attribute__((ext_vector_type(4))) float f32x4;

__device__ __forceinline__ float wred_sum(float v) {
  #pragma unroll
  for (int off = 32; off; off >>= 1) v += __shfl_xor(v, off, 64);
  return v;
}

__device__ __forceinline__ float bflo(unsigned u) {
  return __uint_as_float(u << 16);
}
__device__ __forceinline__ float bfhi(unsigned u) {
  return __uint_as_float(u & 0xFFFF0000u);
}

// ---------------------------------------------------------------------------
// Kernel 1: lhs/rhs reductions; also writes xT[b][n][t][f] bf16
// ---------------------------------------------------------------------------
__global__ __launch_bounds__(256) void k_lhs_rhs(
    const float* __restrict__ x, const float* __restrict__ W1,
    const float* __restrict__ W2, const float* __restrict__ W3,
    float* __restrict__ lhs, float* __restrict__ rhsS,
    unsigned short* __restrict__ xT)   // may be null
{
  int unit = blockIdx.x * 4 + (threadIdx.x >> 6);   // b*512 + n
  int lane = threadIdx.x & 63;
  int b = unit >> 9, n = unit & 511;

  const float* xb = x + ((size_t)b * TT * NN + n) * FF + lane;
  float xv[12];
  #pragma unroll
  for (int t = 0; t < 12; ++t) xv[t] = xb[(size_t)t * NN * FF];

  if (xT) {
    unsigned short* xo = xT + (size_t)unit * (TT * FF) + lane;
    #pragma unroll
    for (int t = 0; t < 12; ++t) {
      __hip_bfloat16 h = __float2bfloat16(xv[t]);   // RTNE
      xo[t * FF] = *reinterpret_cast<unsigned short*>(&h);
    }
  }

  float r1 = 0.f;
  #pragma unroll
  for (int t = 0; t < 12; ++t) r1 += xv[t] * W1[t];

  float w3 = W3[lane];

  float myl = 0.f, myr = 0.f;
  #pragma unroll
  for (int t = 0; t < 12; ++t) {
    float a = r1 * W2[lane * 12 + t];
    float c = xv[t] * w3;
    a = wred_sum(a);
    c = wred_sum(c);
    if (lane == t) { myl = a; myr = c; }
  }
  if (lane < 12) {
    lhs[(size_t)unit * 12 + lane]  = myl;
    rhsS[(size_t)unit * 12 + lane] = myr;
  }
}

// ---------------------------------------------------------------------------
// Kernel 2: beT[m,k] = be[k,m]; extra block builds KF (bf16 K fragments).
// ---------------------------------------------------------------------------
__global__ __launch_bounds__(256) void k_transpose(
    const float* __restrict__ be, float* __restrict__ beT,
    const float* __restrict__ K, unsigned short* __restrict__ KF)
{
  if (blockIdx.x == NN * NN / 256) {
    if (KF) {
      for (int idx = threadIdx.x; idx < 512; idx += 256) {
        int frag = idx >> 6, l = idx & 63;
        int kk = frag >> 2, nt = frag & 3;
        int u = nt * 16 + (l & 15);
        unsigned short* dst = KF + (size_t)idx * 8;
        for (int e = 0; e < 8; ++e) {
          int f = kk * 32 + (l >> 4) * 8 + e;
          __hip_bfloat16 h = __float2bfloat16(K[f * 64 + u]);
          dst[e] = *reinterpret_cast<unsigned short*>(&h);
        }
      }
    }
    return;
  }
  int i = blockIdx.x * 256 + threadIdx.x;  // 262144 total
  int k = i >> 9, m = i & 511;
  beT[m * 512 + k] = be[i];
}

// ---------------------------------------------------------------------------
// Kernel 3: row-wise compaction of mask A (deterministic, ordered by m)
// ---------------------------------------------------------------------------
__global__ void k_build_idx(const float* __restrict__ A,
                            int* __restrict__ nnz, int* __restrict__ cidx)
{
  int j = blockIdx.x;
  int lane = threadIdx.x;  // 64 threads
  unsigned long long lt = (1ull << lane) - 1ull;
  int base = 0;
  for (int c = 0; c < 8; ++c) {
    int m = c * 64 + lane;
    bool p = A[(size_t)j * 512 + m] > 0.5f;
    unsigned long long mask = __ballot(p);
    int pos = base + __popcll(mask & lt);
    if (p && pos < MAXNZ) cidx[j * MAXNZ + pos] = m;
    base += __popcll(mask);
  }
  if (lane == 0) nnz[j] = base > MAXNZ ? MAXNZ : base;
}

// ---------------------------------------------------------------------------
// Kernel 4: column lists
// ---------------------------------------------------------------------------
__global__ void k_build_col(const int* __restrict__ nnz, const int* __restrict__ cidx,
                            int* __restrict__ ccnt, unsigned* __restrict__ colj)
{
  int j = blockIdx.x;
  int lane = threadIdx.x;
  int cnt = nnz[j];
  for (int s = lane; s < cnt; s += 64) {
    int m = cidx[j * MAXNZ + s];
    int pos = atomicAdd(&ccnt[m], 1);
    if (pos < MAXNZ) colj[m * MAXNZ + pos] = (unsigned)j | ((unsigned)s << 16);
  }
}

// ---------------------------------------------------------------------------
// Kernel 5 (v4): product + sigmoid + masked E — single-pass structure.
//   R16 evidence: v3 at 87us, VALUBusy 37%, occ 37% — latency/barrier-bound
//   (8 barriers/block; grid = exactly one residency round -> tail decay).
//   v4: ONE sigmoid pass (16 cols -> sL[16][512] f32, 32 KB) + ONE E phase
//   (2 barriers total). Each 16-lane group owns a whole column, walks its
//   ~27 entries with 2-entry ILP (16 independent dwordx4 streams in flight).
//   LDS 33 KB -> 4 blocks/CU, grid runs 2 rounds (smoother tail), 64 groups/
//   CU x 8-deep MLP for latency coverage.
// ---------------------------------------------------------------------------
__global__ __launch_bounds__(256) void k_product_E4(
    const float* __restrict__ lhs, const float* __restrict__ rhsS,
    const float* __restrict__ beT, const float* __restrict__ Ve,
    const int* __restrict__ ccnt, const unsigned* __restrict__ colj,
    float* __restrict__ evals)
{
  int b  = blockIdx.x;   // 0..63
  int mc = blockIdx.y;   // 0..31 (16 m-columns each)

  __shared__ __align__(16) float sL[16][512];   // 32 KB
  __shared__ float rh[16 * 12];

  int tid = threadIdx.x;

  // lhs rows for k0=tid, k1=tid+256 -> registers (one-time load)
  float l0[12], l1[12];
  {
    const float* p0 = lhs + ((size_t)b * 512 + tid) * 12;
    const float* p1 = lhs + ((size_t)b * 512 + tid + 256) * 12;
    #pragma unroll
    for (int t = 0; t < 12; ++t) { l0[t] = p0[t]; l1[t] = p1[t]; }
  }
  if (tid < 192) rh[tid] = rhsS[((size_t)b * 512 + mc * 16) * 12 + tid];
  __syncthreads();

  // ---- single sigmoid pass: all 16 columns ----
  #pragma unroll 4
  for (int mm = 0; mm < 16; ++mm) {
    int m = mc * 16 + mm;
    float p0 = beT[m * 512 + tid];
    float p1 = beT[m * 512 + tid + 256];
    const float* rw = &rh[mm * 12];
    #pragma unroll
    for (int t = 0; t < 12; ++t) {
      p0 = fmaf(l0[t], rw[t], p0);
      p1 = fmaf(l1[t], rw[t], p1);
    }
    sL[mm][tid]       = 1.0f / (1.0f + __expf(-p0));
    sL[mm][tid + 256] = 1.0f / (1.0f + __expf(-p1));
  }
  __syncthreads();

  // ---- single E phase: group gi owns column mc*16+gi ----
  int gi = tid >> 4, lg = tid & 15;
  int m = mc * 16 + gi;
  int cnt = ccnt[m];
  if (cnt > MAXNZ) cnt = MAXNZ;
  const float4* sw4 = (const float4*)sL[gi];

  int e = 0;
  for (; e + 1 < cnt; e += 2) {
    unsigned pk0 = colj[m * MAXNZ + e];
    unsigned pk1 = colj[m * MAXNZ + e + 1];
    int j0 = pk0 & 0xffff, s0 = (int)(pk0 >> 16);
    int j1 = pk1 & 0xffff, s1 = (int)(pk1 >> 16);
    const float4* va = (const float4*)(Ve + (size_t)j0 * 512);
    const float4* vb = (const float4*)(Ve + (size_t)j1 * 512);
    float a = 0.f, c = 0.f;
    #pragma unroll
    for (int i = 0; i < 8; ++i) {
      float4 s4 = sw4[lg + 16 * i];
      float4 v4 = va[lg + 16 * i];
      float4 w4 = vb[lg + 16 * i];
      a = fmaf(v4.x, s4.x, a); a = fmaf(v4.y, s4.y, a);
      a = fmaf(v4.z, s4.z, a); a = fmaf(v4.w, s4.w, a);
      c = fmaf(w4.x, s4.x, c); c = fmaf(w4.y, s4.y, c);
      c = fmaf(w4.z, s4.z, c); c = fmaf(w4.w, s4.w, c);
    }
    #pragma unroll
    for (int off = 8; off; off >>= 1) {
      a += __shfl_xor(a, off, 64);
      c += __shfl_xor(c, off, 64);
    }
    if (lg == 0) {
      evals[((size_t)b * 512 + j0) * MAXNZ + s0] = a;
      evals[((size_t)b * 512 + j1) * MAXNZ + s1] = c;
    }
  }
  if (e < cnt) {
    unsigned pk0 = colj[m * MAXNZ + e];
    int j0 = pk0 & 0xffff, s0 = (int)(pk0 >> 16);
    const float4* va = (const float4*)(Ve + (size_t)j0 * 512);
    float a = 0.f;
    #pragma unroll
    for (int i = 0; i < 8; ++i) {
      float4 s4 = sw4[lg + 16 * i];
      float4 v4 = va[lg + 16 * i];
      a = fmaf(v4.x, s4.x, a); a = fmaf(v4.y, s4.y, a);
      a = fmaf(v4.z, s4.z, a); a = fmaf(v4.w, s4.w, a);
    }
    #pragma unroll
    for (int off = 8; off; off >>= 1) a += __shfl_xor(a, off, 64);
    if (lg == 0) evals[((size_t)b * 512 + j0) * MAXNZ + s0] = a;
  }
}

// ---------------------------------------------------------------------------
// Kernel 6 (v12): wave per (b,j). Phase A = xT bf16 gather + fused softmax.
//   Phase B = MFMA (8x mfma_f32_16x16x32_bf16).  (R16-measured, below 87us.)
// XCD swizzle: grid = 8192, sbid = (bid&7)*1024 + (bid>>3) bijective.
// ---------------------------------------------------------------------------
__global__ __launch_bounds__(256) void k_out12(
    const unsigned short* __restrict__ xT,
    const int* __restrict__ nnz, const int* __restrict__ cidx,
    const float* __restrict__ evals,
    const unsigned short* __restrict__ KF, const float* __restrict__ bias,
    float* __restrict__ out)
{
  int tid = threadIdx.x;
  int wv = tid >> 6, lane = tid & 63;
  int bid = blockIdx.x;
  int sbid = (bid & 7) * 1024 + (bid >> 3);  // bijective on [0,8192)
  int unit = sbid * 4 + wv;                  // b*512 + j
  int b = unit >> 9, j = unit & 511;

  __shared__ unsigned short convB[4][16][80];  // bf16, row stride 160 B
  __shared__ float valL[4][MAXNZ];
  __shared__ int   idxL[4][MAXNZ];

  int cnt = nnz[j];
  for (int s = lane; s < cnt; s += 64) {
    idxL[wv][s] = cidx[j * MAXNZ + s];
    valL[wv][s] = evals[(size_t)unit * MAXNZ + s];
  }
  // ---- fused masked softmax over this wave's slots (wave-local) ----
  {
    float v0 = lane < cnt        ? valL[wv][lane]      : -__builtin_inff();
    float v1 = (lane + 64) < cnt ? valL[wv][lane + 64] : -__builtin_inff();
    float mx = fmaxf(v0, v1);
    #pragma unroll
    for (int off = 32; off; off >>= 1) mx = fmaxf(mx, __shfl_xor(mx, off, 64));
    float e0 = lane < cnt        ? __expf(v0 - mx) : 0.f;
    float e1 = (lane + 64) < cnt ? __expf(v1 - mx) : 0.f;
    float ssum = wred_sum(e0 + e1);
    float inv = 1.0f / ssum;
    if (lane < cnt)        valL[wv][lane]      = e0 * inv;
    if ((lane + 64) < cnt) valL[wv][lane + 64] = e1 * inv;
  }

  // ---- phase A: bf16 gather from xT (contiguous, imm-offset) ----
  float2 acc[6];
  #pragma unroll
  for (int i = 0; i < 6; ++i) acc[i] = make_float2(0.f, 0.f);

  const unsigned* xb = reinterpret_cast<const unsigned*>(
      xT + (size_t)b * NN * (TT * FF));

  int s = 0;
  for (; s + 1 < cnt; s += 2) {
    int   k0 = idxL[wv][s],     k1 = idxL[wv][s + 1];
    float v0 = valL[wv][s],     v1 = valL[wv][s + 1];
    const unsigned* p0 = xb + k0 * 384 + lane;
    const unsigned* p1 = xb + k1 * 384 + lane;
    unsigned a0 = p0[0],   a1 = p0[64],  a2 = p0[128],
             a3 = p0[192], a4 = p0[256], a5 = p0[320];
    unsigned c0 = p1[0],   c1 = p1[64],  c2 = p1[128],
             c3 = p1[192], c4 = p1[256], c5 = p1[320];
    acc[0].x = fmaf(v0, bflo(a0), acc[0].x); acc[0].y = fmaf(v0, bfhi(a0), acc[0].y);
    acc[1].x = fmaf(v0, bflo(a1), acc[1].x); acc[1].y = fmaf(v0, bfhi(a1), acc[1].y);
    acc[2].x = fmaf(v0, bflo(a2), acc[2].x); acc[2].y = fmaf(v0, bfhi(a2), acc[2].y);
    acc[3].x = fmaf(v0, bflo(a3), acc[3].x); acc[3].y = fmaf(v0, bfhi(a3), acc[3].y);
    acc[4].x = fmaf(v0, bflo(a4), acc[4].x); acc[4].y = fmaf(v0, bfhi(a4), acc[4].y);
    acc[5].x = fmaf(v0, bflo(a5), acc[5].x); acc[5].y = fmaf(v0, bfhi(a5), acc[5].y);
    acc[0].x = fmaf(v1, bflo(c0), acc[0].x); acc[0].y = fmaf(v1, bfhi(c0), acc[0].y);
    acc[1].x = fmaf(v1, bflo(c1), acc[1].x); acc[1].y = fmaf(v1, bfhi(c1), acc[1].y);
    acc[2].x = fmaf(v1, bflo(c2), acc[2].x); acc[2].y = fmaf(v1, bfhi(c2), acc[2].y);
    acc[3].x = fmaf(v1, bflo(c3), acc[3].x); acc[3].y = fmaf(v1, bfhi(c3), acc[3].y);
    acc[4].x = fmaf(v1, bflo(c4), acc[4].x); acc[4].y = fmaf(v1, bfhi(c4), acc[4].y);
    acc[5].x = fmaf(v1, bflo(c5), acc[5].x); acc[5].y = fmaf(v1, bfhi(c5), acc[5].y);
  }
  if (s < cnt) {
    int   k0 = idxL[wv][s];
    float v0 = valL[wv][s];
    const unsigned* p0 = xb + k0 * 384 + lane;
    unsigned a0 = p0[0],   a1 = p0[64],  a2 = p0[128],
             a3 = p0[192], a4 = p0[256], a5 = p0[320];
    acc[0].x = fmaf(v0, bflo(a0), acc[0].x); acc[0].y = fmaf(v0, bfhi(a0), acc[0].y);
    acc[1].x = fmaf(v0, bflo(a1), acc[1].x); acc[1].y = fmaf(v0, bfhi(a1), acc[1].y);
    acc[2].x = fmaf(v0, bflo(a2), acc[2].x); acc[2].y = fmaf(v0, bfhi(a2), acc[2].y);
    acc[3].x = fmaf(v0, bflo(a3), acc[3].x); acc[3].y = fmaf(v0, bfhi(a3), acc[3].y);
    acc[4].x = fmaf(v0, bflo(a4), acc[4].x); acc[4].y = fmaf(v0, bfhi(a4), acc[4].y);
    acc[5].x = fmaf(v0, bflo(a5), acc[5].x); acc[5].y = fmaf(v0, bfhi(a5), acc[5].y);
  }

  // ---- stage conv to LDS as bf16 (acc[i] -> t = 2i+half, f = 2fl,2fl+1) ----
  int half = lane >> 5, fl = lane & 31;
  {
    unsigned short* cb = &convB[wv][0][0];
    #pragma unroll
    for (int i = 0; i < 6; ++i) {
      int t = 2 * i + half;
      __hip_bfloat16 hx = __float2bfloat16(acc[i].x);
      __hip_bfloat16 hy = __float2bfloat16(acc[i].y);
      unsigned pkd = (unsigned)*reinterpret_cast<unsigned short*>(&hx)
                   | ((unsigned)*reinterpret_cast<unsigned short*>(&hy) << 16);
      *reinterpret_cast<unsigned*>(&cb[t * 80 + fl * 2]) = pkd;
    }
  }

  // ---- phase B: 8x MFMA ----
  int arow = lane & 15, agrp = lane >> 4;
  bf16x8 afrag0 = *reinterpret_cast<const bf16x8*>(&convB[wv][arow][agrp * 8]);
  bf16x8 afrag1 = *reinterpret_cast<const bf16x8*>(&convB[wv][arow][32 + agrp * 8]);
  const bf16x8* kf = reinterpret_cast<const bf16x8*>(KF);

  #pragma unroll
  for (int nt = 0; nt < 4; ++nt) {
    f32x4 accT = {0.f, 0.f, 0.f, 0.f};
    accT = __builtin_amdgcn_mfma_f32_16x16x32_bf16(afrag0, kf[(0 * 4 + nt) * 64 + lane], accT, 0, 0, 0);
    accT = __builtin_amdgcn_mfma_f32_16x16x32_bf16(afrag1, kf[(1 * 4 + nt) * 64 + lane], accT, 0, 0, 0);
    int u = nt * 16 + arow;
    float bb = bias[u];
    #pragma unroll
    for (int r = 0; r < 4; ++r) {
      int t = agrp * 4 + r;   // D row = (lane>>4)*4 + reg (HW-verified)
      if (t < 12)
        out[((size_t)(b * TT + t) * NN + j) * UU + u] = accT[r] + bb;
    }
  }
}

// ---------------------------------------------------------------------------
// Kernel 6 fallback (fp32 scalar gather + fused softmax + fmaf phase B)
// ---------------------------------------------------------------------------
__global__ __launch_bounds__(256) void k_out3f(
    const float* __restrict__ x,
    const int* __restrict__ nnz, const int* __restrict__ cidx,
    const float* __restrict__ evals,
    const float* __restrict__ K, const float* __restrict__ bias,
    float* __restrict__ out)
{
  int wv = threadIdx.x >> 6, lane = threadIdx.x & 63;
  int bid = blockIdx.x;
  int sbid = (bid & 7) * 1024 + (bid >> 3);
  int unit = sbid * 4 + wv;
  int b = unit >> 9, j = unit & 511;

  __shared__ float convL[4][12][64];
  __shared__ float valL[4][MAXNZ];
  __shared__ int   idxL[4][MAXNZ];

  int cnt = nnz[j];
  for (int s = lane; s < cnt; s += 64) {
    idxL[wv][s] = cidx[j * MAXNZ + s];
    valL[wv][s] = evals[(size_t)unit * MAXNZ + s];
  }
  {
    float v0 = lane < cnt        ? valL[wv][lane]      : -__builtin_inff();
    float v1 = (lane + 64) < cnt ? valL[wv][lane + 64] : -__builtin_inff();
    float mx = fmaxf(v0, v1);
    #pragma unroll
    for (int off = 32; off; off >>= 1) mx = fmaxf(mx, __shfl_xor(mx, off, 64));
    float e0 = lane < cnt        ? __expf(v0 - mx) : 0.f;
    float e1 = (lane + 64) < cnt ? __expf(v1 - mx) : 0.f;
    float ssum = wred_sum(e0 + e1);
    float inv = 1.0f / ssum;
    if (lane < cnt)        valL[wv][lane]      = e0 * inv;
    if ((lane + 64) < cnt) valL[wv][lane + 64] = e1 * inv;
  }

  float acc[12];
  #pragma unroll
  for (int t = 0; t < 12; ++t) acc[t] = 0.f;

  const float* xb = x + (size_t)b * TT * NN * FF + lane;
  for (int s = 0; s < cnt; ++s) {
    float v = valL[wv][s];
    const float* xk = xb + (size_t)idxL[wv][s] * FF;
    #pragma unroll
    for (int t = 0; t < 12; ++t)
      acc[t] = fmaf(v, xk[(size_t)t * NN * FF], acc[t]);
  }
  #pragma unroll
  for (int t = 0; t < 12; ++t) convL[wv][t][lane] = acc[t];

  float bs = bias[lane];
  float o[12];
  #pragma unroll
  for (int t = 0; t < 12; ++t) o[t] = bs;
  __syncthreads();

  #pragma unroll
  for (int ft = 0; ft < 4; ++ft) {
    float kc[16];
    #pragma unroll
    for (int i = 0; i < 16; ++i) kc[i] = K[(ft * 16 + i) * 64 + lane];
    #pragma unroll
    for (int t = 0; t < 12; ++t) {
      const float4* cv = (const float4*)&convL[wv][t][ft * 16];
      float4 c0 = cv[0], c1 = cv[1], c2 = cv[2], c3 = cv[3];
      float o_ = o[t];
      o_ = fmaf(c0.x, kc[0],  o_); o_ = fmaf(c0.y, kc[1],  o_);
      o_ = fmaf(c0.z, kc[2],  o_); o_ = fmaf(c0.w, kc[3],  o_);
      o_ = fmaf(c1.x, kc[4],  o_); o_ = fmaf(c1.y, kc[5],  o_);
      o_ = fmaf(c1.z, kc[6],  o_); o_ = fmaf(c1.w, kc[7],  o_);
      o_ = fmaf(c2.x, kc[8],  o_); o_ = fmaf(c2.y, kc[9],  o_);
      o_ = fmaf(c2.z, kc[10], o_); o_ = fmaf(c2.w, kc[11], o_);
      o_ = fmaf(c3.x, kc[12], o_); o_ = fmaf(c3.y, kc[13], o_);
      o_ = fmaf(c3.z, kc[14], o_); o_ = fmaf(c3.w, kc[15], o_);
      o[t] = o_;
    }
  }

  #pragma unroll
  for (int t = 0; t < 12; ++t)
    out[((size_t)(b * TT + t) * NN + j) * UU + lane] = o[t];
}

// ---------------------------------------------------------------------------
extern "C" void kernel_launch(void* const* d_in, const int* in_sizes, int n_in,
                              void* d_out, int out_size, void* d_ws, size_t ws_size,
                              hipStream_t stream)
{
  const float* x    = (const float*)d_in[0];  // (B,T,N,F)
  const float* A    = (const float*)d_in[1];  // (N,N)
  const float* W1   = (const float*)d_in[2];  // (T,1)
  const float* W2   = (const float*)d_in[3];  // (F,T)
  const float* W3   = (const float*)d_in[4];  // (F,1)
  const float* Ve   = (const float*)d_in[5];  // (N,N)
  const float* be   = (const float*)d_in[6];  // (N,N)
  const float* K    = (const float*)d_in[7];  // (F,U)
  const float* bias = (const float*)d_in[8];  // (U,)
  float* out = (float*)d_out;

  char* ws = (char*)d_ws;
  float* lhs   = (float*)ws + OF_LHS;
  float* rhsS  = (float*)ws + OF_RHS;
  float* beT   = (float*)ws + OF_BET;
  float* evals = (float*)ws + OF_EVALS;
  int*      nnz  = (int*)(ws + OB_NNZ);
  int*      cidx = (int*)(ws + OB_CIDX);
  int*      ccnt = (int*)(ws + OB_CCNT);
  unsigned* colj = (unsigned*)(ws + OB_COLJ);
  unsigned short* xT = (unsigned short*)(ws + OB_XT);
  unsigned short* KF = (unsigned short*)(ws + OB_KF);

  const bool use_xt = ws_size >= OB_KF + KF_BYTES;

  hipMemsetAsync(ccnt, 0, NN * sizeof(int), stream);

  // 1. lhs / rhs (+ transposed bf16 copy of x)
  k_lhs_rhs<<<dim3(BB * NN / 4), dim3(256), 0, stream>>>(
      x, W1, W2, W3, lhs, rhsS, use_xt ? xT : nullptr);
  // 2. transpose be (+ KF fragment build)
  k_transpose<<<dim3(NN * NN / 256 + 1), dim3(256), 0, stream>>>(
      be, beT, K, use_xt ? KF : nullptr);
  // 3. row index lists
  k_build_idx<<<dim3(NN), dim3(64), 0, stream>>>(A, nnz, cidx);
  // 4. column lists
  k_build_col<<<dim3(NN), dim3(64), 0, stream>>>(nnz, cidx, ccnt, colj);
  // 5. product + sigmoid + masked E (v4: single-pass, 2-entry ILP)
  k_product_E4<<<dim3(BB, NN / 16), dim3(256), 0, stream>>>(lhs, rhsS, beT, Ve, ccnt, colj, evals);
  // 6. sparse conv + fused softmax + MFMA output GEMM
  if (use_xt)
    k_out12<<<dim3(BB * NN / 4), dim3(256), 0, stream>>>(xT, nnz, cidx, evals, KF, bias, out);
  else
    k_out3f<<<dim3(BB * NN / 4), dim3(256), 0, stream>>>(x, nnz, cidx, evals, K, bias, out);
}

// Round 18
// 221.924 us; speedup vs baseline: 1.0077x; 1.0077x over previous
//
#include <hip/hip_runtime.h>
#include <hip/hip_bf16.h>
#include <cstdint>

// Problem constants
constexpr int BB = 64;    // batch
constexpr int TT = 12;    // time
constexpr int NN = 512;   // nodes
constexpr int FF = 64;    // features
constexpr int UU = 64;    // units
constexpr int MAXNZ = 128;

// ---------------------------------------------------------------------------
// Workspace layout (bytes):
//   floats: lhs 0 / rhs 393216f / beT 786432f / evals 1048576f
//   ints:   nnz 20971520 / cidx 20973568 / ccnt 21235712 / colj 21237760
//   xT (B,N,T,F) bf16 : 21516288, 50331648 B
//   KF (8 frags x 64 lanes x 8 bf16) : 71847936, 8192 B
// ---------------------------------------------------------------------------
constexpr size_t OF_LHS   = 0;
constexpr size_t OF_RHS   = 393216;
constexpr size_t OF_BET   = 786432;
constexpr size_t OF_EVALS = 1048576;
constexpr size_t OB_NNZ   = 20971520;
constexpr size_t OB_CIDX  = 20973568;
constexpr size_t OB_CCNT  = 21235712;
constexpr size_t OB_COLJ  = 21237760;
constexpr size_t OB_XT    = 21516288;
constexpr size_t XT_BYTES = (size_t)BB * NN * TT * FF * 2;  // 50331648
constexpr size_t OB_KF    = 71847936;
constexpr size_t KF_BYTES = 8 * 64 * 8 * 2;                 // 8192

typedef __attribute__((ext_vector_type(8))) short bf16x8;   // 8 bf16 = 4 VGPRs
typedef __attribute__((ext_vector_type(4))) float f32x4;

__device__ __forceinline__ float wred_sum(float v) {
  #pragma unroll
  for (int off = 32; off; off >>= 1) v += __shfl_xor(v, off, 64);
  return v;
}

__device__ __forceinline__ float bflo(unsigned u) {
  return __uint_as_float(u << 16);
}
__device__ __forceinline__ float bfhi(unsigned u) {
  return __uint_as_float(u & 0xFFFF0000u);
}

// ---------------------------------------------------------------------------
// Kernel 1: lhs/rhs reductions; also writes xT[b][n][t][f] bf16
// ---------------------------------------------------------------------------
__global__ __launch_bounds__(256) void k_lhs_rhs(
    const float* __restrict__ x, const float* __restrict__ W1,
    const float* __restrict__ W2, const float* __restrict__ W3,
    float* __restrict__ lhs, float* __restrict__ rhsS,
    unsigned short* __restrict__ xT)   // may be null
{
  int unit = blockIdx.x * 4 + (threadIdx.x >> 6);   // b*512 + n
  int lane = threadIdx.x & 63;
  int b = unit >> 9, n = unit & 511;

  const float* xb = x + ((size_t)b * TT * NN + n) * FF + lane;
  float xv[12];
  #pragma unroll
  for (int t = 0; t < 12; ++t) xv[t] = xb[(size_t)t * NN * FF];

  if (xT) {
    unsigned short* xo = xT + (size_t)unit * (TT * FF) + lane;
    #pragma unroll
    for (int t = 0; t < 12; ++t) {
      __hip_bfloat16 h = __float2bfloat16(xv[t]);   // RTNE
      xo[t * FF] = *reinterpret_cast<unsigned short*>(&h);
    }
  }

  float r1 = 0.f;
  #pragma unroll
  for (int t = 0; t < 12; ++t) r1 += xv[t] * W1[t];

  float w3 = W3[lane];

  float myl = 0.f, myr = 0.f;
  #pragma unroll
  for (int t = 0; t < 12; ++t) {
    float a = r1 * W2[lane * 12 + t];
    float c = xv[t] * w3;
    a = wred_sum(a);
    c = wred_sum(c);
    if (lane == t) { myl = a; myr = c; }
  }
  if (lane < 12) {
    lhs[(size_t)unit * 12 + lane]  = myl;
    rhsS[(size_t)unit * 12 + lane] = myr;
  }
}

// ---------------------------------------------------------------------------
// Kernel 2: beT[m,k] = be[k,m]; extra block builds KF (bf16 K fragments).
// ---------------------------------------------------------------------------
__global__ __launch_bounds__(256) void k_transpose(
    const float* __restrict__ be, float* __restrict__ beT,
    const float* __restrict__ K, unsigned short* __restrict__ KF)
{
  if (blockIdx.x == NN * NN / 256) {
    if (KF) {
      for (int idx = threadIdx.x; idx < 512; idx += 256) {
        int frag = idx >> 6, l = idx & 63;
        int kk = frag >> 2, nt = frag & 3;
        int u = nt * 16 + (l & 15);
        unsigned short* dst = KF + (size_t)idx * 8;
        for (int e = 0; e < 8; ++e) {
          int f = kk * 32 + (l >> 4) * 8 + e;
          __hip_bfloat16 h = __float2bfloat16(K[f * 64 + u]);
          dst[e] = *reinterpret_cast<unsigned short*>(&h);
        }
      }
    }
    return;
  }
  int i = blockIdx.x * 256 + threadIdx.x;  // 262144 total
  int k = i >> 9, m = i & 511;
  beT[m * 512 + k] = be[i];
}

// ---------------------------------------------------------------------------
// Kernel 3: row-wise compaction of mask A (deterministic, ordered by m)
// ---------------------------------------------------------------------------
__global__ void k_build_idx(const float* __restrict__ A,
                            int* __restrict__ nnz, int* __restrict__ cidx)
{
  int j = blockIdx.x;
  int lane = threadIdx.x;  // 64 threads
  unsigned long long lt = (1ull << lane) - 1ull;
  int base = 0;
  for (int c = 0; c < 8; ++c) {
    int m = c * 64 + lane;
    bool p = A[(size_t)j * 512 + m] > 0.5f;
    unsigned long long mask = __ballot(p);
    int pos = base + __popcll(mask & lt);
    if (p && pos < MAXNZ) cidx[j * MAXNZ + pos] = m;
    base += __popcll(mask);
  }
  if (lane == 0) nnz[j] = base > MAXNZ ? MAXNZ : base;
}

// ---------------------------------------------------------------------------
// Kernel 4: column lists
// ---------------------------------------------------------------------------
__global__ void k_build_col(const int* __restrict__ nnz, const int* __restrict__ cidx,
                            int* __restrict__ ccnt, unsigned* __restrict__ colj)
{
  int j = blockIdx.x;
  int lane = threadIdx.x;
  int cnt = nnz[j];
  for (int s = lane; s < cnt; s += 64) {
    int m = cidx[j * MAXNZ + s];
    int pos = atomicAdd(&ccnt[m], 1);
    if (pos < MAXNZ) colj[m * MAXNZ + pos] = (unsigned)j | ((unsigned)s << 16);
  }
}

// ---------------------------------------------------------------------------
// Kernel 5 (v4): product + sigmoid + masked E — single-pass structure.
//   R16 evidence: v3 at 87us, VALUBusy 37%, occ 37% — latency/barrier-bound
//   (8 barriers/block; grid = exactly one residency round -> tail decay).
//   v4: ONE sigmoid pass (16 cols -> sL[16][512] f32, 32 KB) + ONE E phase
//   (2 barriers total). Each 16-lane group owns a whole column, walks its
//   ~27 entries with 2-entry ILP (16 independent dwordx4 streams in flight).
//   LDS 33 KB -> 4 blocks/CU, grid runs 2 rounds (smoother tail), 64 groups/
//   CU x 8-deep MLP for latency coverage.
// ---------------------------------------------------------------------------
__global__ __launch_bounds__(256) void k_product_E4(
    const float* __restrict__ lhs, const float* __restrict__ rhsS,
    const float* __restrict__ beT, const float* __restrict__ Ve,
    const int* __restrict__ ccnt, const unsigned* __restrict__ colj,
    float* __restrict__ evals)
{
  int b  = blockIdx.x;   // 0..63
  int mc = blockIdx.y;   // 0..31 (16 m-columns each)

  __shared__ __align__(16) float sL[16][512];   // 32 KB
  __shared__ float rh[16 * 12];

  int tid = threadIdx.x;

  // lhs rows for k0=tid, k1=tid+256 -> registers (one-time load)
  float l0[12], l1[12];
  {
    const float* p0 = lhs + ((size_t)b * 512 + tid) * 12;
    const float* p1 = lhs + ((size_t)b * 512 + tid + 256) * 12;
    #pragma unroll
    for (int t = 0; t < 12; ++t) { l0[t] = p0[t]; l1[t] = p1[t]; }
  }
  if (tid < 192) rh[tid] = rhsS[((size_t)b * 512 + mc * 16) * 12 + tid];
  __syncthreads();

  // ---- single sigmoid pass: all 16 columns ----
  #pragma unroll 4
  for (int mm = 0; mm < 16; ++mm) {
    int m = mc * 16 + mm;
    float p0 = beT[m * 512 + tid];
    float p1 = beT[m * 512 + tid + 256];
    const float* rw = &rh[mm * 12];
    #pragma unroll
    for (int t = 0; t < 12; ++t) {
      p0 = fmaf(l0[t], rw[t], p0);
      p1 = fmaf(l1[t], rw[t], p1);
    }
    sL[mm][tid]       = 1.0f / (1.0f + __expf(-p0));
    sL[mm][tid + 256] = 1.0f / (1.0f + __expf(-p1));
  }
  __syncthreads();

  // ---- single E phase: group gi owns column mc*16+gi ----
  int gi = tid >> 4, lg = tid & 15;
  int m = mc * 16 + gi;
  int cnt = ccnt[m];
  if (cnt > MAXNZ) cnt = MAXNZ;
  const float4* sw4 = (const float4*)sL[gi];

  int e = 0;
  for (; e + 1 < cnt; e += 2) {
    unsigned pk0 = colj[m * MAXNZ + e];
    unsigned pk1 = colj[m * MAXNZ + e + 1];
    int j0 = pk0 & 0xffff, s0 = (int)(pk0 >> 16);
    int j1 = pk1 & 0xffff, s1 = (int)(pk1 >> 16);
    const float4* va = (const float4*)(Ve + (size_t)j0 * 512);
    const float4* vb = (const float4*)(Ve + (size_t)j1 * 512);
    float a = 0.f, c = 0.f;
    #pragma unroll
    for (int i = 0; i < 8; ++i) {
      float4 s4 = sw4[lg + 16 * i];
      float4 v4 = va[lg + 16 * i];
      float4 w4 = vb[lg + 16 * i];
      a = fmaf(v4.x, s4.x, a); a = fmaf(v4.y, s4.y, a);
      a = fmaf(v4.z, s4.z, a); a = fmaf(v4.w, s4.w, a);
      c = fmaf(w4.x, s4.x, c); c = fmaf(w4.y, s4.y, c);
      c = fmaf(w4.z, s4.z, c); c = fmaf(w4.w, s4.w, c);
    }
    #pragma unroll
    for (int off = 8; off; off >>= 1) {
      a += __shfl_xor(a, off, 64);
      c += __shfl_xor(c, off, 64);
    }
    if (lg == 0) {
      evals[((size_t)b * 512 + j0) * MAXNZ + s0] = a;
      evals[((size_t)b * 512 + j1) * MAXNZ + s1] = c;
    }
  }
  if (e < cnt) {
    unsigned pk0 = colj[m * MAXNZ + e];
    int j0 = pk0 & 0xffff, s0 = (int)(pk0 >> 16);
    const float4* va = (const float4*)(Ve + (size_t)j0 * 512);
    float a = 0.f;
    #pragma unroll
    for (int i = 0; i < 8; ++i) {
      float4 s4 = sw4[lg + 16 * i];
      float4 v4 = va[lg + 16 * i];
      a = fmaf(v4.x, s4.x, a); a = fmaf(v4.y, s4.y, a);
      a = fmaf(v4.z, s4.z, a); a = fmaf(v4.w, s4.w, a);
    }
    #pragma unroll
    for (int off = 8; off; off >>= 1) a += __shfl_xor(a, off, 64);
    if (lg == 0) evals[((size_t)b * 512 + j0) * MAXNZ + s0] = a;
  }
}

// ---------------------------------------------------------------------------
// Kernel 6 (v12): wave per (b,j). Phase A = xT bf16 gather + fused softmax.
//   Phase B = MFMA (8x mfma_f32_16x16x32_bf16).  (R16-measured, below 87us.)
// XCD swizzle: grid = 8192, sbid = (bid&7)*1024 + (bid>>3) bijective.
// ---------------------------------------------------------------------------
__global__ __launch_bounds__(256) void k_out12(
    const unsigned short* __restrict__ xT,
    const int* __restrict__ nnz, const int* __restrict__ cidx,
    const float* __restrict__ evals,
    const unsigned short* __restrict__ KF, const float* __restrict__ bias,
    float* __restrict__ out)
{
  int tid = threadIdx.x;
  int wv = tid >> 6, lane = tid & 63;
  int bid = blockIdx.x;
  int sbid = (bid & 7) * 1024 + (bid >> 3);  // bijective on [0,8192)
  int unit = sbid * 4 + wv;                  // b*512 + j
  int b = unit >> 9, j = unit & 511;

  __shared__ unsigned short convB[4][16][80];  // bf16, row stride 160 B
  __shared__ float valL[4][MAXNZ];
  __shared__ int   idxL[4][MAXNZ];

  int cnt = nnz[j];
  for (int s = lane; s < cnt; s += 64) {
    idxL[wv][s] = cidx[j * MAXNZ + s];
    valL[wv][s] = evals[(size_t)unit * MAXNZ + s];
  }
  // ---- fused masked softmax over this wave's slots (wave-local) ----
  {
    float v0 = lane < cnt        ? valL[wv][lane]      : -__builtin_inff();
    float v1 = (lane + 64) < cnt ? valL[wv][lane + 64] : -__builtin_inff();
    float mx = fmaxf(v0, v1);
    #pragma unroll
    for (int off = 32; off; off >>= 1) mx = fmaxf(mx, __shfl_xor(mx, off, 64));
    float e0 = lane < cnt        ? __expf(v0 - mx) : 0.f;
    float e1 = (lane + 64) < cnt ? __expf(v1 - mx) : 0.f;
    float ssum = wred_sum(e0 + e1);
    float inv = 1.0f / ssum;
    if (lane < cnt)        valL[wv][lane]      = e0 * inv;
    if ((lane + 64) < cnt) valL[wv][lane + 64] = e1 * inv;
  }

  // ---- phase A: bf16 gather from xT (contiguous, imm-offset) ----
  float2 acc[6];
  #pragma unroll
  for (int i = 0; i < 6; ++i) acc[i] = make_float2(0.f, 0.f);

  const unsigned* xb = reinterpret_cast<const unsigned*>(
      xT + (size_t)b * NN * (TT * FF));

  int s = 0;
  for (; s + 1 < cnt; s += 2) {
    int   k0 = idxL[wv][s],     k1 = idxL[wv][s + 1];
    float v0 = valL[wv][s],     v1 = valL[wv][s + 1];
    const unsigned* p0 = xb + k0 * 384 + lane;
    const unsigned* p1 = xb + k1 * 384 + lane;
    unsigned a0 = p0[0],   a1 = p0[64],  a2 = p0[128],
             a3 = p0[192], a4 = p0[256], a5 = p0[320];
    unsigned c0 = p1[0],   c1 = p1[64],  c2 = p1[128],
             c3 = p1[192], c4 = p1[256], c5 = p1[320];
    acc[0].x = fmaf(v0, bflo(a0), acc[0].x); acc[0].y = fmaf(v0, bfhi(a0), acc[0].y);
    acc[1].x = fmaf(v0, bflo(a1), acc[1].x); acc[1].y = fmaf(v0, bfhi(a1), acc[1].y);
    acc[2].x = fmaf(v0, bflo(a2), acc[2].x); acc[2].y = fmaf(v0, bfhi(a2), acc[2].y);
    acc[3].x = fmaf(v0, bflo(a3), acc[3].x); acc[3].y = fmaf(v0, bfhi(a3), acc[3].y);
    acc[4].x = fmaf(v0, bflo(a4), acc[4].x); acc[4].y = fmaf(v0, bfhi(a4), acc[4].y);
    acc[5].x = fmaf(v0, bflo(a5), acc[5].x); acc[5].y = fmaf(v0, bfhi(a5), acc[5].y);
    acc[0].x = fmaf(v1, bflo(c0), acc[0].x); acc[0].y = fmaf(v1, bfhi(c0), acc[0].y);
    acc[1].x = fmaf(v1, bflo(c1), acc[1].x); acc[1].y = fmaf(v1, bfhi(c1), acc[1].y);
    acc[2].x = fmaf(v1, bflo(c2), acc[2].x); acc[2].y = fmaf(v1, bfhi(c2), acc[2].y);
    acc[3].x = fmaf(v1, bflo(c3), acc[3].x); acc[3].y = fmaf(v1, bfhi(c3), acc[3].y);
    acc[4].x = fmaf(v1, bflo(c4), acc[4].x); acc[4].y = fmaf(v1, bfhi(c4), acc[4].y);
    acc[5].x = fmaf(v1, bflo(c5), acc[5].x); acc[5].y = fmaf(v1, bfhi(c5), acc[5].y);
  }
  if (s < cnt) {
    int   k0 = idxL[wv][s];
    float v0 = valL[wv][s];
    const unsigned* p0 = xb + k0 * 384 + lane;
    unsigned a0 = p0[0],   a1 = p0[64],  a2 = p0[128],
             a3 = p0[192], a4 = p0[256], a5 = p0[320];
    acc[0].x = fmaf(v0, bflo(a0), acc[0].x); acc[0].y = fmaf(v0, bfhi(a0), acc[0].y);
    acc[1].x = fmaf(v0, bflo(a1), acc[1].x); acc[1].y = fmaf(v0, bfhi(a1), acc[1].y);
    acc[2].x = fmaf(v0, bflo(a2), acc[2].x); acc[2].y = fmaf(v0, bfhi(a2), acc[2].y);
    acc[3].x = fmaf(v0, bflo(a3), acc[3].x); acc[3].y = fmaf(v0, bfhi(a3), acc[3].y);
    acc[4].x = fmaf(v0, bflo(a4), acc[4].x); acc[4].y = fmaf(v0, bfhi(a4), acc[4].y);
    acc[5].x = fmaf(v0, bflo(a5), acc[5].x); acc[5].y = fmaf(v0, bfhi(a5), acc[5].y);
  }

  // ---- stage conv to LDS as bf16 (acc[i] -> t = 2i+half, f = 2fl,2fl+1) ----
  int half = lane >> 5, fl = lane & 31;
  {
    unsigned short* cb = &convB[wv][0][0];
    #pragma unroll
    for (int i = 0; i < 6; ++i) {
      int t = 2 * i + half;
      __hip_bfloat16 hx = __float2bfloat16(acc[i].x);
      __hip_bfloat16 hy = __float2bfloat16(acc[i].y);
      unsigned pkd = (unsigned)*reinterpret_cast<unsigned short*>(&hx)
                   | ((unsigned)*reinterpret_cast<unsigned short*>(&hy) << 16);
      *reinterpret_cast<unsigned*>(&cb[t * 80 + fl * 2]) = pkd;
    }
  }

  // ---- phase B: 8x MFMA ----
  int arow = lane & 15, agrp = lane >> 4;
  bf16x8 afrag0 = *reinterpret_cast<const bf16x8*>(&convB[wv][arow][agrp * 8]);
  bf16x8 afrag1 = *reinterpret_cast<const bf16x8*>(&convB[wv][arow][32 + agrp * 8]);
  const bf16x8* kf = reinterpret_cast<const bf16x8*>(KF);

  #pragma unroll
  for (int nt = 0; nt < 4; ++nt) {
    f32x4 accT = {0.f, 0.f, 0.f, 0.f};
    accT = __builtin_amdgcn_mfma_f32_16x16x32_bf16(afrag0, kf[(0 * 4 + nt) * 64 + lane], accT, 0, 0, 0);
    accT = __builtin_amdgcn_mfma_f32_16x16x32_bf16(afrag1, kf[(1 * 4 + nt) * 64 + lane], accT, 0, 0, 0);
    int u = nt * 16 + arow;
    float bb = bias[u];
    #pragma unroll
    for (int r = 0; r < 4; ++r) {
      int t = agrp * 4 + r;   // D row = (lane>>4)*4 + reg (HW-verified)
      if (t < 12)
        out[((size_t)(b * TT + t) * NN + j) * UU + u] = accT[r] + bb;
    }
  }
}

// ---------------------------------------------------------------------------
// Kernel 6 fallback (fp32 scalar gather + fused softmax + fmaf phase B)
// ---------------------------------------------------------------------------
__global__ __launch_bounds__(256) void k_out3f(
    const float* __restrict__ x,
    const int* __restrict__ nnz, const int* __restrict__ cidx,
    const float* __restrict__ evals,
    const float* __restrict__ K, const float* __restrict__ bias,
    float* __restrict__ out)
{
  int wv = threadIdx.x >> 6, lane = threadIdx.x & 63;
  int bid = blockIdx.x;
  int sbid = (bid & 7) * 1024 + (bid >> 3);
  int unit = sbid * 4 + wv;
  int b = unit >> 9, j = unit & 511;

  __shared__ float convL[4][12][64];
  __shared__ float valL[4][MAXNZ];
  __shared__ int   idxL[4][MAXNZ];

  int cnt = nnz[j];
  for (int s = lane; s < cnt; s += 64) {
    idxL[wv][s] = cidx[j * MAXNZ + s];
    valL[wv][s] = evals[(size_t)unit * MAXNZ + s];
  }
  {
    float v0 = lane < cnt        ? valL[wv][lane]      : -__builtin_inff();
    float v1 = (lane + 64) < cnt ? valL[wv][lane + 64] : -__builtin_inff();
    float mx = fmaxf(v0, v1);
    #pragma unroll
    for (int off = 32; off; off >>= 1) mx = fmaxf(mx, __shfl_xor(mx, off, 64));
    float e0 = lane < cnt        ? __expf(v0 - mx) : 0.f;
    float e1 = (lane + 64) < cnt ? __expf(v1 - mx) : 0.f;
    float ssum = wred_sum(e0 + e1);
    float inv = 1.0f / ssum;
    if (lane < cnt)        valL[wv][lane]      = e0 * inv;
    if ((lane + 64) < cnt) valL[wv][lane + 64] = e1 * inv;
  }

  float acc[12];
  #pragma unroll
  for (int t = 0; t < 12; ++t) acc[t] = 0.f;

  const float* xb = x + (size_t)b * TT * NN * FF + lane;
  for (int s = 0; s < cnt; ++s) {
    float v = valL[wv][s];
    const float* xk = xb + (size_t)idxL[wv][s] * FF;
    #pragma unroll
    for (int t = 0; t < 12; ++t)
      acc[t] = fmaf(v, xk[(size_t)t * NN * FF], acc[t]);
  }
  #pragma unroll
  for (int t = 0; t < 12; ++t) convL[wv][t][lane] = acc[t];

  float bs = bias[lane];
  float o[12];
  #pragma unroll
  for (int t = 0; t < 12; ++t) o[t] = bs;
  __syncthreads();

  #pragma unroll
  for (int ft = 0; ft < 4; ++ft) {
    float kc[16];
    #pragma unroll
    for (int i = 0; i < 16; ++i) kc[i] = K[(ft * 16 + i) * 64 + lane];
    #pragma unroll
    for (int t = 0; t < 12; ++t) {
      const float4* cv = (const float4*)&convL[wv][t][ft * 16];
      float4 c0 = cv[0], c1 = cv[1], c2 = cv[2], c3 = cv[3];
      float o_ = o[t];
      o_ = fmaf(c0.x, kc[0],  o_); o_ = fmaf(c0.y, kc[1],  o_);
      o_ = fmaf(c0.z, kc[2],  o_); o_ = fmaf(c0.w, kc[3],  o_);
      o_ = fmaf(c1.x, kc[4],  o_); o_ = fmaf(c1.y, kc[5],  o_);
      o_ = fmaf(c1.z, kc[6],  o_); o_ = fmaf(c1.w, kc[7],  o_);
      o_ = fmaf(c2.x, kc[8],  o_); o_ = fmaf(c2.y, kc[9],  o_);
      o_ = fmaf(c2.z, kc[10], o_); o_ = fmaf(c2.w, kc[11], o_);
      o_ = fmaf(c3.x, kc[12], o_); o_ = fmaf(c3.y, kc[13], o_);
      o_ = fmaf(c3.z, kc[14], o_); o_ = fmaf(c3.w, kc[15], o_);
      o[t] = o_;
    }
  }

  #pragma unroll
  for (int t = 0; t < 12; ++t)
    out[((size_t)(b * TT + t) * NN + j) * UU + lane] = o[t];
}

// ---------------------------------------------------------------------------
extern "C" void kernel_launch(void* const* d_in, const int* in_sizes, int n_in,
                              void* d_out, int out_size, void* d_ws, size_t ws_size,
                              hipStream_t stream)
{
  const float* x    = (const float*)d_in[0];  // (B,T,N,F)
  const float* A    = (const float*)d_in[1];  // (N,N)
  const float* W1   = (const float*)d_in[2];  // (T,1)
  const float* W2   = (const float*)d_in[3];  // (F,T)
  const float* W3   = (const float*)d_in[4];  // (F,1)
  const float* Ve   = (const float*)d_in[5];  // (N,N)
  const float* be   = (const float*)d_in[6];  // (N,N)
  const float* K    = (const float*)d_in[7];  // (F,U)
  const float* bias = (const float*)d_in[8];  // (U,)
  float* out = (float*)d_out;

  char* ws = (char*)d_ws;
  float* lhs   = (float*)ws + OF_LHS;
  float* rhsS  = (float*)ws + OF_RHS;
  float* beT   = (float*)ws + OF_BET;
  float* evals = (float*)ws + OF_EVALS;
  int*      nnz  = (int*)(ws + OB_NNZ);
  int*      cidx = (int*)(ws + OB_CIDX);
  int*      ccnt = (int*)(ws + OB_CCNT);
  unsigned* colj = (unsigned*)(ws + OB_COLJ);
  unsigned short* xT = (unsigned short*)(ws + OB_XT);
  unsigned short* KF = (unsigned short*)(ws + OB_KF);

  const bool use_xt = ws_size >= OB_KF + KF_BYTES;

  hipMemsetAsync(ccnt, 0, NN * sizeof(int), stream);

  // 1. lhs / rhs (+ transposed bf16 copy of x)
  k_lhs_rhs<<<dim3(BB * NN / 4), dim3(256), 0, stream>>>(
      x, W1, W2, W3, lhs, rhsS, use_xt ? xT : nullptr);
  // 2. transpose be (+ KF fragment build)
  k_transpose<<<dim3(NN * NN / 256 + 1), dim3(256), 0, stream>>>(
      be, beT, K, use_xt ? KF : nullptr);
  // 3. row index lists
  k_build_idx<<<dim3(NN), dim3(64), 0, stream>>>(A, nnz, cidx);
  // 4. column lists
  k_build_col<<<dim3(NN), dim3(64), 0, stream>>>(nnz, cidx, ccnt, colj);
  // 5. product + sigmoid + masked E (v4: single-pass, 2-entry ILP)
  k_product_E4<<<dim3(BB, NN / 16), dim3(256), 0, stream>>>(lhs, rhsS, beT, Ve, ccnt, colj, evals);
  // 6. sparse conv + fused softmax + MFMA output GEMM
  if (use_xt)
    k_out12<<<dim3(BB * NN / 4), dim3(256), 0, stream>>>(xT, nnz, cidx, evals, KF, bias, out);
  else
    k_out3f<<<dim3(BB * NN / 4), dim3(256), 0, stream>>>(x, nnz, cidx, evals, K, bias, out);
}

// Round 19
// 218.531 us; speedup vs baseline: 1.0234x; 1.0155x over previous
//
#include <hip/hip_runtime.h>
#include <hip/hip_bf16.h>
#include <cstdint>

// Problem constants
constexpr int BB = 64;    // batch
constexpr int TT = 12;    // time
constexpr int NN = 512;   // nodes
constexpr int FF = 64;    // features
constexpr int UU = 64;    // units
constexpr int MAXNZ = 128;

// ---------------------------------------------------------------------------
// Workspace layout (bytes):
//   floats: lhs 0 / rhs 393216f / beT 786432f / evals 1048576f
//   ints:   nnz 20971520 / cidx 20973568 / ccnt 21235712 / colj 21237760
//   xT (B,N,T,F) bf16 : 21516288, 50331648 B
//   KF (8 frags x 64 lanes x 8 bf16) : 71847936, 8192 B
// ---------------------------------------------------------------------------
constexpr size_t OF_LHS   = 0;
constexpr size_t OF_RHS   = 393216;
constexpr size_t OF_BET   = 786432;
constexpr size_t OF_EVALS = 1048576;
constexpr size_t OB_NNZ   = 20971520;
constexpr size_t OB_CIDX  = 20973568;
constexpr size_t OB_CCNT  = 21235712;
constexpr size_t OB_COLJ  = 21237760;
constexpr size_t OB_XT    = 21516288;
constexpr size_t XT_BYTES = (size_t)BB * NN * TT * FF * 2;  // 50331648
constexpr size_t OB_KF    = 71847936;
constexpr size_t KF_BYTES = 8 * 64 * 8 * 2;                 // 8192

typedef __attribute__((ext_vector_type(8))) short bf16x8;   // 8 bf16 = 4 VGPRs
typedef __attribute__((ext_vector_type(4))) float f32x4;

__device__ __forceinline__ float wred_sum(float v) {
  #pragma unroll
  for (int off = 32; off; off >>= 1) v += __shfl_xor(v, off, 64);
  return v;
}

__device__ __forceinline__ float bflo(unsigned u) {
  return __uint_as_float(u << 16);
}
__device__ __forceinline__ float bfhi(unsigned u) {
  return __uint_as_float(u & 0xFFFF0000u);
}

// ---------------------------------------------------------------------------
// Kernel 1: lhs/rhs reductions; also writes xT[b][n][t][f] bf16
// ---------------------------------------------------------------------------
__global__ __launch_bounds__(256) void k_lhs_rhs(
    const float* __restrict__ x, const float* __restrict__ W1,
    const float* __restrict__ W2, const float* __restrict__ W3,
    float* __restrict__ lhs, float* __restrict__ rhsS,
    unsigned short* __restrict__ xT)   // may be null
{
  int unit = blockIdx.x * 4 + (threadIdx.x >> 6);   // b*512 + n
  int lane = threadIdx.x & 63;
  int b = unit >> 9, n = unit & 511;

  const float* xb = x + ((size_t)b * TT * NN + n) * FF + lane;
  float xv[12];
  #pragma unroll
  for (int t = 0; t < 12; ++t) xv[t] = xb[(size_t)t * NN * FF];

  if (xT) {
    unsigned short* xo = xT + (size_t)unit * (TT * FF) + lane;
    #pragma unroll
    for (int t = 0; t < 12; ++t) {
      __hip_bfloat16 h = __float2bfloat16(xv[t]);   // RTNE
      xo[t * FF] = *reinterpret_cast<unsigned short*>(&h);
    }
  }

  float r1 = 0.f;
  #pragma unroll
  for (int t = 0; t < 12; ++t) r1 += xv[t] * W1[t];

  float w3 = W3[lane];

  float myl = 0.f, myr = 0.f;
  #pragma unroll
  for (int t = 0; t < 12; ++t) {
    float a = r1 * W2[lane * 12 + t];
    float c = xv[t] * w3;
    a = wred_sum(a);
    c = wred_sum(c);
    if (lane == t) { myl = a; myr = c; }
  }
  if (lane < 12) {
    lhs[(size_t)unit * 12 + lane]  = myl;
    rhsS[(size_t)unit * 12 + lane] = myr;
  }
}

// ---------------------------------------------------------------------------
// Kernel 2: beT[m,k] = be[k,m]; extra block builds KF (bf16 K fragments).
// ---------------------------------------------------------------------------
__global__ __launch_bounds__(256) void k_transpose(
    const float* __restrict__ be, float* __restrict__ beT,
    const float* __restrict__ K, unsigned short* __restrict__ KF)
{
  if (blockIdx.x == NN * NN / 256) {
    if (KF) {
      for (int idx = threadIdx.x; idx < 512; idx += 256) {
        int frag = idx >> 6, l = idx & 63;
        int kk = frag >> 2, nt = frag & 3;
        int u = nt * 16 + (l & 15);
        unsigned short* dst = KF + (size_t)idx * 8;
        for (int e = 0; e < 8; ++e) {
          int f = kk * 32 + (l >> 4) * 8 + e;
          __hip_bfloat16 h = __float2bfloat16(K[f * 64 + u]);
          dst[e] = *reinterpret_cast<unsigned short*>(&h);
        }
      }
    }
    return;
  }
  int i = blockIdx.x * 256 + threadIdx.x;  // 262144 total
  int k = i >> 9, m = i & 511;
  beT[m * 512 + k] = be[i];
}

// ---------------------------------------------------------------------------
// Kernel 3: row-wise compaction of mask A (deterministic, ordered by m)
// ---------------------------------------------------------------------------
__global__ void k_build_idx(const float* __restrict__ A,
                            int* __restrict__ nnz, int* __restrict__ cidx)
{
  int j = blockIdx.x;
  int lane = threadIdx.x;  // 64 threads
  unsigned long long lt = (1ull << lane) - 1ull;
  int base = 0;
  for (int c = 0; c < 8; ++c) {
    int m = c * 64 + lane;
    bool p = A[(size_t)j * 512 + m] > 0.5f;
    unsigned long long mask = __ballot(p);
    int pos = base + __popcll(mask & lt);
    if (p && pos < MAXNZ) cidx[j * MAXNZ + pos] = m;
    base += __popcll(mask);
  }
  if (lane == 0) nnz[j] = base > MAXNZ ? MAXNZ : base;
}

// ---------------------------------------------------------------------------
// Kernel 4: column lists
// ---------------------------------------------------------------------------
__global__ void k_build_col(const int* __restrict__ nnz, const int* __restrict__ cidx,
                            int* __restrict__ ccnt, unsigned* __restrict__ colj)
{
  int j = blockIdx.x;
  int lane = threadIdx.x;
  int cnt = nnz[j];
  for (int s = lane; s < cnt; s += 64) {
    int m = cidx[j * MAXNZ + s];
    int pos = atomicAdd(&ccnt[m], 1);
    if (pos < MAXNZ) colj[m * MAXNZ + pos] = (unsigned)j | ((unsigned)s << 16);
  }
}

// ---------------------------------------------------------------------------
// Kernel 5 (v5): product + sigmoid + masked E.
//   R18 evidence: v4 (33.8 KB LDS) stuck at 4 blocks/CU (occ 35%) AND had
//   intra-wave divergence (each group a different column -> wave runs to
//   max cnt of 4). v5: MCH=8 -> sL[8][512] fp32 = 16 KB -> 8 blocks/CU
//   (2x TLP, grid 4096 = two clean residency rounds); E phase back to
//   E3's uniform split: wave w owns columns w, w+4; its 4 groups stride-4
//   over the SAME column's entries (uniform trip counts), 2-entry ILP.
// ---------------------------------------------------------------------------
__global__ __launch_bounds__(256) void k_product_E5(
    const float* __restrict__ lhs, const float* __restrict__ rhsS,
    const float* __restrict__ beT, const float* __restrict__ Ve,
    const int* __restrict__ ccnt, const unsigned* __restrict__ colj,
    float* __restrict__ evals)
{
  int b  = blockIdx.x;   // 0..63
  int mc = blockIdx.y;   // 0..63 (8 m-columns each)

  __shared__ __align__(16) float sL[8][512];   // 16 KB
  __shared__ float rh[8 * 12];

  int tid = threadIdx.x;
  int wave = tid >> 6, lane = tid & 63;
  int grp = lane >> 4, lg = lane & 15;

  // lhs rows for k0=tid, k1=tid+256 -> registers (one-time load)
  float l0[12], l1[12];
  {
    const float* p0 = lhs + ((size_t)b * 512 + tid) * 12;
    const float* p1 = p0 + 256 * 12;
    #pragma unroll
    for (int t = 0; t < 12; ++t) { l0[t] = p0[t]; l1[t] = p1[t]; }
  }
  if (tid < 96) rh[tid] = rhsS[((size_t)b * 512 + mc * 8) * 12 + tid];
  __syncthreads();

  // ---- single sigmoid pass: 8 columns ----
  #pragma unroll
  for (int mm = 0; mm < 8; ++mm) {
    int m = mc * 8 + mm;
    float q0 = beT[m * 512 + tid];
    float q1 = beT[m * 512 + tid + 256];
    const float* rw = &rh[mm * 12];
    #pragma unroll
    for (int t = 0; t < 12; ++t) {
      q0 = fmaf(l0[t], rw[t], q0);
      q1 = fmaf(l1[t], rw[t], q1);
    }
    sL[mm][tid]       = 1.0f / (1.0f + __expf(-q0));
    sL[mm][tid + 256] = 1.0f / (1.0f + __expf(-q1));
  }
  __syncthreads();

  // ---- E phase: wave handles columns wave, wave+4 (uniform per-wave) ----
  for (int cc = 0; cc < 2; ++cc) {
    int mm = wave + cc * 4;
    int m = mc * 8 + mm;
    int cnt = ccnt[m];
    if (cnt > MAXNZ) cnt = MAXNZ;
    const float4* sw4 = (const float4*)sL[mm];
    const unsigned* cj = colj + m * MAXNZ;

    // group grp takes entries grp, grp+4, grp+8, ... ; 2 per iteration
    int e0 = grp;
    for (; e0 + 4 < cnt; e0 += 8) {
      unsigned pk0 = cj[e0], pk1 = cj[e0 + 4];
      int j0 = pk0 & 0xffff, s0 = (int)(pk0 >> 16);
      int j1 = pk1 & 0xffff, s1 = (int)(pk1 >> 16);
      const float4* va = (const float4*)(Ve + (size_t)j0 * 512);
      const float4* vb = (const float4*)(Ve + (size_t)j1 * 512);
      float a = 0.f, c = 0.f;
      #pragma unroll
      for (int i = 0; i < 8; ++i) {
        float4 s4 = sw4[lg + 16 * i];
        float4 v4 = va[lg + 16 * i];
        float4 w4 = vb[lg + 16 * i];
        a = fmaf(v4.x, s4.x, a); a = fmaf(v4.y, s4.y, a);
        a = fmaf(v4.z, s4.z, a); a = fmaf(v4.w, s4.w, a);
        c = fmaf(w4.x, s4.x, c); c = fmaf(w4.y, s4.y, c);
        c = fmaf(w4.z, s4.z, c); c = fmaf(w4.w, s4.w, c);
      }
      #pragma unroll
      for (int off = 8; off; off >>= 1) {
        a += __shfl_xor(a, off, 64);
        c += __shfl_xor(c, off, 64);
      }
      if (lg == 0) {
        evals[((size_t)b * 512 + j0) * MAXNZ + s0] = a;
        evals[((size_t)b * 512 + j1) * MAXNZ + s1] = c;
      }
    }
    if (e0 < cnt) {
      unsigned pk0 = cj[e0];
      int j0 = pk0 & 0xffff, s0 = (int)(pk0 >> 16);
      const float4* va = (const float4*)(Ve + (size_t)j0 * 512);
      float a = 0.f;
      #pragma unroll
      for (int i = 0; i < 8; ++i) {
        float4 s4 = sw4[lg + 16 * i];
        float4 v4 = va[lg + 16 * i];
        a = fmaf(v4.x, s4.x, a); a = fmaf(v4.y, s4.y, a);
        a = fmaf(v4.z, s4.z, a); a = fmaf(v4.w, s4.w, a);
      }
      #pragma unroll
      for (int off = 8; off; off >>= 1) a += __shfl_xor(a, off, 64);
      if (lg == 0) evals[((size_t)b * 512 + j0) * MAXNZ + s0] = a;
    }
  }
}

// ---------------------------------------------------------------------------
// Kernel 6 (v12): wave per (b,j). Phase A = xT bf16 gather + fused softmax.
//   Phase B = MFMA (8x mfma_f32_16x16x32_bf16).
// XCD swizzle: grid = 8192, sbid = (bid&7)*1024 + (bid>>3) bijective.
// ---------------------------------------------------------------------------
__global__ __launch_bounds__(256) void k_out12(
    const unsigned short* __restrict__ xT,
    const int* __restrict__ nnz, const int* __restrict__ cidx,
    const float* __restrict__ evals,
    const unsigned short* __restrict__ KF, const float* __restrict__ bias,
    float* __restrict__ out)
{
  int tid = threadIdx.x;
  int wv = tid >> 6, lane = tid & 63;
  int bid = blockIdx.x;
  int sbid = (bid & 7) * 1024 + (bid >> 3);  // bijective on [0,8192)
  int unit = sbid * 4 + wv;                  // b*512 + j
  int b = unit >> 9, j = unit & 511;

  __shared__ unsigned short convB[4][16][80];  // bf16, row stride 160 B
  __shared__ float valL[4][MAXNZ];
  __shared__ int   idxL[4][MAXNZ];

  int cnt = nnz[j];
  for (int s = lane; s < cnt; s += 64) {
    idxL[wv][s] = cidx[j * MAXNZ + s];
    valL[wv][s] = evals[(size_t)unit * MAXNZ + s];
  }
  // ---- fused masked softmax over this wave's slots (wave-local) ----
  {
    float v0 = lane < cnt        ? valL[wv][lane]      : -__builtin_inff();
    float v1 = (lane + 64) < cnt ? valL[wv][lane + 64] : -__builtin_inff();
    float mx = fmaxf(v0, v1);
    #pragma unroll
    for (int off = 32; off; off >>= 1) mx = fmaxf(mx, __shfl_xor(mx, off, 64));
    float e0 = lane < cnt        ? __expf(v0 - mx) : 0.f;
    float e1 = (lane + 64) < cnt ? __expf(v1 - mx) : 0.f;
    float ssum = wred_sum(e0 + e1);
    float inv = 1.0f / ssum;
    if (lane < cnt)        valL[wv][lane]      = e0 * inv;
    if ((lane + 64) < cnt) valL[wv][lane + 64] = e1 * inv;
  }

  // ---- phase A: bf16 gather from xT (contiguous, imm-offset) ----
  float2 acc[6];
  #pragma unroll
  for (int i = 0; i < 6; ++i) acc[i] = make_float2(0.f, 0.f);

  const unsigned* xb = reinterpret_cast<const unsigned*>(
      xT + (size_t)b * NN * (TT * FF));

  int s = 0;
  for (; s + 1 < cnt; s += 2) {
    int   k0 = idxL[wv][s],     k1 = idxL[wv][s + 1];
    float v0 = valL[wv][s],     v1 = valL[wv][s + 1];
    const unsigned* p0 = xb + k0 * 384 + lane;
    const unsigned* p1 = xb + k1 * 384 + lane;
    unsigned a0 = p0[0],   a1 = p0[64],  a2 = p0[128],
             a3 = p0[192], a4 = p0[256], a5 = p0[320];
    unsigned c0 = p1[0],   c1 = p1[64],  c2 = p1[128],
             c3 = p1[192], c4 = p1[256], c5 = p1[320];
    acc[0].x = fmaf(v0, bflo(a0), acc[0].x); acc[0].y = fmaf(v0, bfhi(a0), acc[0].y);
    acc[1].x = fmaf(v0, bflo(a1), acc[1].x); acc[1].y = fmaf(v0, bfhi(a1), acc[1].y);
    acc[2].x = fmaf(v0, bflo(a2), acc[2].x); acc[2].y = fmaf(v0, bfhi(a2), acc[2].y);
    acc[3].x = fmaf(v0, bflo(a3), acc[3].x); acc[3].y = fmaf(v0, bfhi(a3), acc[3].y);
    acc[4].x = fmaf(v0, bflo(a4), acc[4].x); acc[4].y = fmaf(v0, bfhi(a4), acc[4].y);
    acc[5].x = fmaf(v0, bflo(a5), acc[5].x); acc[5].y = fmaf(v0, bfhi(a5), acc[5].y);
    acc[0].x = fmaf(v1, bflo(c0), acc[0].x); acc[0].y = fmaf(v1, bfhi(c0), acc[0].y);
    acc[1].x = fmaf(v1, bflo(c1), acc[1].x); acc[1].y = fmaf(v1, bfhi(c1), acc[1].y);
    acc[2].x = fmaf(v1, bflo(c2), acc[2].x); acc[2].y = fmaf(v1, bfhi(c2), acc[2].y);
    acc[3].x = fmaf(v1, bflo(c3), acc[3].x); acc[3].y = fmaf(v1, bfhi(c3), acc[3].y);
    acc[4].x = fmaf(v1, bflo(c4), acc[4].x); acc[4].y = fmaf(v1, bfhi(c4), acc[4].y);
    acc[5].x = fmaf(v1, bflo(c5), acc[5].x); acc[5].y = fmaf(v1, bfhi(c5), acc[5].y);
  }
  if (s < cnt) {
    int   k0 = idxL[wv][s];
    float v0 = valL[wv][s];
    const unsigned* p0 = xb + k0 * 384 + lane;
    unsigned a0 = p0[0],   a1 = p0[64],  a2 = p0[128],
             a3 = p0[192], a4 = p0[256], a5 = p0[320];
    acc[0].x = fmaf(v0, bflo(a0), acc[0].x); acc[0].y = fmaf(v0, bfhi(a0), acc[0].y);
    acc[1].x = fmaf(v0, bflo(a1), acc[1].x); acc[1].y = fmaf(v0, bfhi(a1), acc[1].y);
    acc[2].x = fmaf(v0, bflo(a2), acc[2].x); acc[2].y = fmaf(v0, bfhi(a2), acc[2].y);
    acc[3].x = fmaf(v0, bflo(a3), acc[3].x); acc[3].y = fmaf(v0, bfhi(a3), acc[3].y);
    acc[4].x = fmaf(v0, bflo(a4), acc[4].x); acc[4].y = fmaf(v0, bfhi(a4), acc[4].y);
    acc[5].x = fmaf(v0, bflo(a5), acc[5].x); acc[5].y = fmaf(v0, bfhi(a5), acc[5].y);
  }

  // ---- stage conv to LDS as bf16 (acc[i] -> t = 2i+half, f = 2fl,2fl+1) ----
  int half = lane >> 5, fl = lane & 31;
  {
    unsigned short* cb = &convB[wv][0][0];
    #pragma unroll
    for (int i = 0; i < 6; ++i) {
      int t = 2 * i + half;
      __hip_bfloat16 hx = __float2bfloat16(acc[i].x);
      __hip_bfloat16 hy = __float2bfloat16(acc[i].y);
      unsigned pkd = (unsigned)*reinterpret_cast<unsigned short*>(&hx)
                   | ((unsigned)*reinterpret_cast<unsigned short*>(&hy) << 16);
      *reinterpret_cast<unsigned*>(&cb[t * 80 + fl * 2]) = pkd;
    }
  }

  // ---- phase B: 8x MFMA ----
  int arow = lane & 15, agrp = lane >> 4;
  bf16x8 afrag0 = *reinterpret_cast<const bf16x8*>(&convB[wv][arow][agrp * 8]);
  bf16x8 afrag1 = *reinterpret_cast<const bf16x8*>(&convB[wv][arow][32 + agrp * 8]);
  const bf16x8* kf = reinterpret_cast<const bf16x8*>(KF);

  #pragma unroll
  for (int nt = 0; nt < 4; ++nt) {
    f32x4 accT = {0.f, 0.f, 0.f, 0.f};
    accT = __builtin_amdgcn_mfma_f32_16x16x32_bf16(afrag0, kf[(0 * 4 + nt) * 64 + lane], accT, 0, 0, 0);
    accT = __builtin_amdgcn_mfma_f32_16x16x32_bf16(afrag1, kf[(1 * 4 + nt) * 64 + lane], accT, 0, 0, 0);
    int u = nt * 16 + arow;
    float bb = bias[u];
    #pragma unroll
    for (int r = 0; r < 4; ++r) {
      int t = agrp * 4 + r;   // D row = (lane>>4)*4 + reg (HW-verified)
      if (t < 12)
        out[((size_t)(b * TT + t) * NN + j) * UU + u] = accT[r] + bb;
    }
  }
}

// ---------------------------------------------------------------------------
// Kernel 6 fallback (fp32 scalar gather + fused softmax + fmaf phase B)
// ---------------------------------------------------------------------------
__global__ __launch_bounds__(256) void k_out3f(
    const float* __restrict__ x,
    const int* __restrict__ nnz, const int* __restrict__ cidx,
    const float* __restrict__ evals,
    const float* __restrict__ K, const float* __restrict__ bias,
    float* __restrict__ out)
{
  int wv = threadIdx.x >> 6, lane = threadIdx.x & 63;
  int bid = blockIdx.x;
  int sbid = (bid & 7) * 1024 + (bid >> 3);
  int unit = sbid * 4 + wv;
  int b = unit >> 9, j = unit & 511;

  __shared__ float convL[4][12][64];
  __shared__ float valL[4][MAXNZ];
  __shared__ int   idxL[4][MAXNZ];

  int cnt = nnz[j];
  for (int s = lane; s < cnt; s += 64) {
    idxL[wv][s] = cidx[j * MAXNZ + s];
    valL[wv][s] = evals[(size_t)unit * MAXNZ + s];
  }
  {
    float v0 = lane < cnt        ? valL[wv][lane]      : -__builtin_inff();
    float v1 = (lane + 64) < cnt ? valL[wv][lane + 64] : -__builtin_inff();
    float mx = fmaxf(v0, v1);
    #pragma unroll
    for (int off = 32; off; off >>= 1) mx = fmaxf(mx, __shfl_xor(mx, off, 64));
    float e0 = lane < cnt        ? __expf(v0 - mx) : 0.f;
    float e1 = (lane + 64) < cnt ? __expf(v1 - mx) : 0.f;
    float ssum = wred_sum(e0 + e1);
    float inv = 1.0f / ssum;
    if (lane < cnt)        valL[wv][lane]      = e0 * inv;
    if ((lane + 64) < cnt) valL[wv][lane + 64] = e1 * inv;
  }

  float acc[12];
  #pragma unroll
  for (int t = 0; t < 12; ++t) acc[t] = 0.f;

  const float* xb = x + (size_t)b * TT * NN * FF + lane;
  for (int s = 0; s < cnt; ++s) {
    float v = valL[wv][s];
    const float* xk = xb + (size_t)idxL[wv][s] * FF;
    #pragma unroll
    for (int t = 0; t < 12; ++t)
      acc[t] = fmaf(v, xk[(size_t)t * NN * FF], acc[t]);
  }
  #pragma unroll
  for (int t = 0; t < 12; ++t) convL[wv][t][lane] = acc[t];

  float bs = bias[lane];
  float o[12];
  #pragma unroll
  for (int t = 0; t < 12; ++t) o[t] = bs;
  __syncthreads();

  #pragma unroll
  for (int ft = 0; ft < 4; ++ft) {
    float kc[16];
    #pragma unroll
    for (int i = 0; i < 16; ++i) kc[i] = K[(ft * 16 + i) * 64 + lane];
    #pragma unroll
    for (int t = 0; t < 12; ++t) {
      const float4* cv = (const float4*)&convL[wv][t][ft * 16];
      float4 c0 = cv[0], c1 = cv[1], c2 = cv[2], c3 = cv[3];
      float o_ = o[t];
      o_ = fmaf(c0.x, kc[0],  o_); o_ = fmaf(c0.y, kc[1],  o_);
      o_ = fmaf(c0.z, kc[2],  o_); o_ = fmaf(c0.w, kc[3],  o_);
      o_ = fmaf(c1.x, kc[4],  o_); o_ = fmaf(c1.y, kc[5],  o_);
      o_ = fmaf(c1.z, kc[6],  o_); o_ = fmaf(c1.w, kc[7],  o_);
      o_ = fmaf(c2.x, kc[8],  o_); o_ = fmaf(c2.y, kc[9],  o_);
      o_ = fmaf(c2.z, kc[10], o_); o_ = fmaf(c2.w, kc[11], o_);
      o_ = fmaf(c3.x, kc[12], o_); o_ = fmaf(c3.y, kc[13], o_);
      o_ = fmaf(c3.z, kc[14], o_); o_ = fmaf(c3.w, kc[15], o_);
      o[t] = o_;
    }
  }

  #pragma unroll
  for (int t = 0; t < 12; ++t)
    out[((size_t)(b * TT + t) * NN + j) * UU + lane] = o[t];
}

// ---------------------------------------------------------------------------
extern "C" void kernel_launch(void* const* d_in, const int* in_sizes, int n_in,
                              void* d_out, int out_size, void* d_ws, size_t ws_size,
                              hipStream_t stream)
{
  const float* x    = (const float*)d_in[0];  // (B,T,N,F)
  const float* A    = (const float*)d_in[1];  // (N,N)
  const float* W1   = (const float*)d_in[2];  // (T,1)
  const float* W2   = (const float*)d_in[3];  // (F,T)
  const float* W3   = (const float*)d_in[4];  // (F,1)
  const float* Ve   = (const float*)d_in[5];  // (N,N)
  const float* be   = (const float*)d_in[6];  // (N,N)
  const float* K    = (const float*)d_in[7];  // (F,U)
  const float* bias = (const float*)d_in[8];  // (U,)
  float* out = (float*)d_out;

  char* ws = (char*)d_ws;
  float* lhs   = (float*)ws + OF_LHS;
  float* rhsS  = (float*)ws + OF_RHS;
  float* beT   = (float*)ws + OF_BET;
  float* evals = (float*)ws + OF_EVALS;
  int*      nnz  = (int*)(ws + OB_NNZ);
  int*      cidx = (int*)(ws + OB_CIDX);
  int*      ccnt = (int*)(ws + OB_CCNT);
  unsigned* colj = (unsigned*)(ws + OB_COLJ);
  unsigned short* xT = (unsigned short*)(ws + OB_XT);
  unsigned short* KF = (unsigned short*)(ws + OB_KF);

  const bool use_xt = ws_size >= OB_KF + KF_BYTES;

  hipMemsetAsync(ccnt, 0, NN * sizeof(int), stream);

  // 1. lhs / rhs (+ transposed bf16 copy of x)
  k_lhs_rhs<<<dim3(BB * NN / 4), dim3(256), 0, stream>>>(
      x, W1, W2, W3, lhs, rhsS, use_xt ? xT : nullptr);
  // 2. transpose be (+ KF fragment build)
  k_transpose<<<dim3(NN * NN / 256 + 1), dim3(256), 0, stream>>>(
      be, beT, K, use_xt ? KF : nullptr);
  // 3. row index lists
  k_build_idx<<<dim3(NN), dim3(64), 0, stream>>>(A, nnz, cidx);
  // 4. column lists
  k_build_col<<<dim3(NN), dim3(64), 0, stream>>>(nnz, cidx, ccnt, colj);
  // 5. product + sigmoid + masked E (v5: MCH=8, 16KB LDS, uniform split)
  k_product_E5<<<dim3(BB, NN / 8), dim3(256), 0, stream>>>(lhs, rhsS, beT, Ve, ccnt, colj, evals);
  // 6. sparse conv + fused softmax + MFMA output GEMM
  if (use_xt)
    k_out12<<<dim3(BB * NN / 4), dim3(256), 0, stream>>>(xT, nnz, cidx, evals, KF, bias, out);
  else
    k_out3f<<<dim3(BB * NN / 4), dim3(256), 0, stream>>>(x, nnz, cidx, evals, K, bias, out);
}

// Round 20
// 217.971 us; speedup vs baseline: 1.0260x; 1.0026x over previous
//
#include <hip/hip_runtime.h>
#include <hip/hip_bf16.h>
#include <cstdint>

// Problem constants
constexpr int BB = 64;    // batch
constexpr int TT = 12;    // time
constexpr int NN = 512;   // nodes
constexpr int FF = 64;    // features
constexpr int UU = 64;    // units
constexpr int MAXNZ = 128;

// ---------------------------------------------------------------------------
// Workspace layout (bytes):
//   floats: lhs 0 / rhs 393216f / beT 786432f / evals 1048576f
//   ints:   nnz 20971520 / cidx 20973568 / ccnt 21235712 / colj 21237760
//   xT (B,N,T,F) bf16 : 21516288, 50331648 B
//   KF (8 frags x 64 lanes x 8 bf16) : 71847936, 8192 B
//   VeB (N,N) bf16 : 71856128, 524288 B     (ws >= 105 MB proven in R12)
// ---------------------------------------------------------------------------
constexpr size_t OF_LHS   = 0;
constexpr size_t OF_RHS   = 393216;
constexpr size_t OF_BET   = 786432;
constexpr size_t OF_EVALS = 1048576;
constexpr size_t OB_NNZ   = 20971520;
constexpr size_t OB_CIDX  = 20973568;
constexpr size_t OB_CCNT  = 21235712;
constexpr size_t OB_COLJ  = 21237760;
constexpr size_t OB_XT    = 21516288;
constexpr size_t XT_BYTES = (size_t)BB * NN * TT * FF * 2;  // 50331648
constexpr size_t OB_KF    = 71847936;
constexpr size_t KF_BYTES = 8 * 64 * 8 * 2;                 // 8192
constexpr size_t OB_VEB   = 71856128;
constexpr size_t VEB_BYTES = (size_t)NN * NN * 2;           // 524288

typedef __attribute__((ext_vector_type(8))) short bf16x8;   // 8 bf16 = 4 VGPRs
typedef __attribute__((ext_vector_type(4))) float f32x4;

__device__ __forceinline__ float wred_sum(float v) {
  #pragma unroll
  for (int off = 32; off; off >>= 1) v += __shfl_xor(v, off, 64);
  return v;
}

__device__ __forceinline__ float bflo(unsigned u) {
  return __uint_as_float(u << 16);
}
__device__ __forceinline__ float bfhi(unsigned u) {
  return __uint_as_float(u & 0xFFFF0000u);
}

// ---------------------------------------------------------------------------
// Kernel 1: lhs/rhs reductions; also writes xT[b][n][t][f] bf16
// ---------------------------------------------------------------------------
__global__ __launch_bounds__(256) void k_lhs_rhs(
    const float* __restrict__ x, const float* __restrict__ W1,
    const float* __restrict__ W2, const float* __restrict__ W3,
    float* __restrict__ lhs, float* __restrict__ rhsS,
    unsigned short* __restrict__ xT)   // may be null
{
  int unit = blockIdx.x * 4 + (threadIdx.x >> 6);   // b*512 + n
  int lane = threadIdx.x & 63;
  int b = unit >> 9, n = unit & 511;

  const float* xb = x + ((size_t)b * TT * NN + n) * FF + lane;
  float xv[12];
  #pragma unroll
  for (int t = 0; t < 12; ++t) xv[t] = xb[(size_t)t * NN * FF];

  if (xT) {
    unsigned short* xo = xT + (size_t)unit * (TT * FF) + lane;
    #pragma unroll
    for (int t = 0; t < 12; ++t) {
      __hip_bfloat16 h = __float2bfloat16(xv[t]);   // RTNE
      xo[t * FF] = *reinterpret_cast<unsigned short*>(&h);
    }
  }

  float r1 = 0.f;
  #pragma unroll
  for (int t = 0; t < 12; ++t) r1 += xv[t] * W1[t];

  float w3 = W3[lane];

  float myl = 0.f, myr = 0.f;
  #pragma unroll
  for (int t = 0; t < 12; ++t) {
    float a = r1 * W2[lane * 12 + t];
    float c = xv[t] * w3;
    a = wred_sum(a);
    c = wred_sum(c);
    if (lane == t) { myl = a; myr = c; }
  }
  if (lane < 12) {
    lhs[(size_t)unit * 12 + lane]  = myl;
    rhsS[(size_t)unit * 12 + lane] = myr;
  }
}

// ---------------------------------------------------------------------------
// Kernel 2: beT[m,k] = be[k,m]; block 1024 builds KF; blocks 1025..1056
// build VeB (bf16 copy of Ve, coalesced).
// ---------------------------------------------------------------------------
__global__ __launch_bounds__(256) void k_transpose(
    const float* __restrict__ be, float* __restrict__ beT,
    const float* __restrict__ K, unsigned short* __restrict__ KF,
    const float* __restrict__ Ve, unsigned short* __restrict__ VeB)
{
  int bid = blockIdx.x;
  if (bid < NN * NN / 256) {
    int i = bid * 256 + threadIdx.x;  // 262144 total
    int k = i >> 9, m = i & 511;
    beT[m * 512 + k] = be[i];
    return;
  }
  if (bid == NN * NN / 256) {
    if (KF) {
      for (int idx = threadIdx.x; idx < 512; idx += 256) {
        int frag = idx >> 6, l = idx & 63;
        int kk = frag >> 2, nt = frag & 3;
        int u = nt * 16 + (l & 15);
        unsigned short* dst = KF + (size_t)idx * 8;
        for (int e = 0; e < 8; ++e) {
          int f = kk * 32 + (l >> 4) * 8 + e;
          __hip_bfloat16 h = __float2bfloat16(K[f * 64 + u]);
          dst[e] = *reinterpret_cast<unsigned short*>(&h);
        }
      }
    }
    return;
  }
  // VeB blocks: 32 blocks x 8192 elements
  if (VeB) {
    int b2 = bid - (NN * NN / 256 + 1);   // 0..31
    #pragma unroll
    for (int i = 0; i < 32; ++i) {
      int idx = b2 * 8192 + i * 256 + threadIdx.x;
      __hip_bfloat16 h = __float2bfloat16(Ve[idx]);
      VeB[idx] = *reinterpret_cast<unsigned short*>(&h);
    }
  }
}

// ---------------------------------------------------------------------------
// Kernel 3: row-wise compaction of mask A (deterministic, ordered by m)
// ---------------------------------------------------------------------------
__global__ void k_build_idx(const float* __restrict__ A,
                            int* __restrict__ nnz, int* __restrict__ cidx)
{
  int j = blockIdx.x;
  int lane = threadIdx.x;  // 64 threads
  unsigned long long lt = (1ull << lane) - 1ull;
  int base = 0;
  for (int c = 0; c < 8; ++c) {
    int m = c * 64 + lane;
    bool p = A[(size_t)j * 512 + m] > 0.5f;
    unsigned long long mask = __ballot(p);
    int pos = base + __popcll(mask & lt);
    if (p && pos < MAXNZ) cidx[j * MAXNZ + pos] = m;
    base += __popcll(mask);
  }
  if (lane == 0) nnz[j] = base > MAXNZ ? MAXNZ : base;
}

// ---------------------------------------------------------------------------
// Kernel 4: column lists
// ---------------------------------------------------------------------------
__global__ void k_build_col(const int* __restrict__ nnz, const int* __restrict__ cidx,
                            int* __restrict__ ccnt, unsigned* __restrict__ colj)
{
  int j = blockIdx.x;
  int lane = threadIdx.x;
  int cnt = nnz[j];
  for (int s = lane; s < cnt; s += 64) {
    int m = cidx[j * MAXNZ + s];
    int pos = atomicAdd(&ccnt[m], 1);
    if (pos < MAXNZ) colj[m * MAXNZ + pos] = (unsigned)j | ((unsigned)s << 16);
  }
}

// ---------------------------------------------------------------------------
// Kernel 5 (v6): product + sigmoid + masked E — E5 structure, bf16 Ve reads.
//   R19 evidence: 86us invariant across E3/E4/E5 structural variants with
//   low VALU (41%) and near-zero HBM -> L2-request-bound on Ve row reads
//   (885K entries x 2KB = 1.77 GB/launch). v6 halves the bytes: VeB bf16,
//   uint2 loads + unpack (same instr count, half L2 traffic).
// ---------------------------------------------------------------------------
__global__ __launch_bounds__(256) void k_product_E6(
    const float* __restrict__ lhs, const float* __restrict__ rhsS,
    const float* __restrict__ beT, const unsigned short* __restrict__ VeB,
    const int* __restrict__ ccnt, const unsigned* __restrict__ colj,
    float* __restrict__ evals)
{
  int b  = blockIdx.x;   // 0..63
  int mc = blockIdx.y;   // 0..63 (8 m-columns each)

  __shared__ __align__(16) float sL[8][512];   // 16 KB
  __shared__ float rh[8 * 12];

  int tid = threadIdx.x;
  int wave = tid >> 6, lane = tid & 63;
  int grp = lane >> 4, lg = lane & 15;

  float l0[12], l1[12];
  {
    const float* p0 = lhs + ((size_t)b * 512 + tid) * 12;
    const float* p1 = p0 + 256 * 12;
    #pragma unroll
    for (int t = 0; t < 12; ++t) { l0[t] = p0[t]; l1[t] = p1[t]; }
  }
  if (tid < 96) rh[tid] = rhsS[((size_t)b * 512 + mc * 8) * 12 + tid];
  __syncthreads();

  // ---- single sigmoid pass: 8 columns ----
  #pragma unroll
  for (int mm = 0; mm < 8; ++mm) {
    int m = mc * 8 + mm;
    float q0 = beT[m * 512 + tid];
    float q1 = beT[m * 512 + tid + 256];
    const float* rw = &rh[mm * 12];
    #pragma unroll
    for (int t = 0; t < 12; ++t) {
      q0 = fmaf(l0[t], rw[t], q0);
      q1 = fmaf(l1[t], rw[t], q1);
    }
    sL[mm][tid]       = 1.0f / (1.0f + __expf(-q0));
    sL[mm][tid + 256] = 1.0f / (1.0f + __expf(-q1));
  }
  __syncthreads();

  // ---- E phase: wave handles columns wave, wave+4 (uniform per-wave) ----
  for (int cc = 0; cc < 2; ++cc) {
    int mm = wave + cc * 4;
    int m = mc * 8 + mm;
    int cnt = ccnt[m];
    if (cnt > MAXNZ) cnt = MAXNZ;
    const float4* sw4 = (const float4*)sL[mm];
    const unsigned* cj = colj + m * MAXNZ;

    int e0 = grp;
    for (; e0 + 4 < cnt; e0 += 8) {
      unsigned pk0 = cj[e0], pk1 = cj[e0 + 4];
      int j0 = pk0 & 0xffff, s0 = (int)(pk0 >> 16);
      int j1 = pk1 & 0xffff, s1 = (int)(pk1 >> 16);
      const uint2* va = (const uint2*)(VeB + (size_t)j0 * 512);
      const uint2* vb = (const uint2*)(VeB + (size_t)j1 * 512);
      float a = 0.f, c = 0.f;
      #pragma unroll
      for (int i = 0; i < 8; ++i) {
        float4 s4 = sw4[lg + 16 * i];
        uint2  u0 = va[lg + 16 * i];
        uint2  u1 = vb[lg + 16 * i];
        a = fmaf(bflo(u0.x), s4.x, a); a = fmaf(bfhi(u0.x), s4.y, a);
        a = fmaf(bflo(u0.y), s4.z, a); a = fmaf(bfhi(u0.y), s4.w, a);
        c = fmaf(bflo(u1.x), s4.x, c); c = fmaf(bfhi(u1.x), s4.y, c);
        c = fmaf(bflo(u1.y), s4.z, c); c = fmaf(bfhi(u1.y), s4.w, c);
      }
      #pragma unroll
      for (int off = 8; off; off >>= 1) {
        a += __shfl_xor(a, off, 64);
        c += __shfl_xor(c, off, 64);
      }
      if (lg == 0) {
        evals[((size_t)b * 512 + j0) * MAXNZ + s0] = a;
        evals[((size_t)b * 512 + j1) * MAXNZ + s1] = c;
      }
    }
    if (e0 < cnt) {
      unsigned pk0 = cj[e0];
      int j0 = pk0 & 0xffff, s0 = (int)(pk0 >> 16);
      const uint2* va = (const uint2*)(VeB + (size_t)j0 * 512);
      float a = 0.f;
      #pragma unroll
      for (int i = 0; i < 8; ++i) {
        float4 s4 = sw4[lg + 16 * i];
        uint2  u0 = va[lg + 16 * i];
        a = fmaf(bflo(u0.x), s4.x, a); a = fmaf(bfhi(u0.x), s4.y, a);
        a = fmaf(bflo(u0.y), s4.z, a); a = fmaf(bfhi(u0.y), s4.w, a);
      }
      #pragma unroll
      for (int off = 8; off; off >>= 1) a += __shfl_xor(a, off, 64);
      if (lg == 0) evals[((size_t)b * 512 + j0) * MAXNZ + s0] = a;
    }
  }
}

// ---------------------------------------------------------------------------
// Kernel 5 fallback (fp32 Ve, E5 structure) — used if ws too small for VeB
// ---------------------------------------------------------------------------
__global__ __launch_bounds__(256) void k_product_E5(
    const float* __restrict__ lhs, const float* __restrict__ rhsS,
    const float* __restrict__ beT, const float* __restrict__ Ve,
    const int* __restrict__ ccnt, const unsigned* __restrict__ colj,
    float* __restrict__ evals)
{
  int b  = blockIdx.x;
  int mc = blockIdx.y;

  __shared__ __align__(16) float sL[8][512];
  __shared__ float rh[8 * 12];

  int tid = threadIdx.x;
  int wave = tid >> 6, lane = tid & 63;
  int grp = lane >> 4, lg = lane & 15;

  float l0[12], l1[12];
  {
    const float* p0 = lhs + ((size_t)b * 512 + tid) * 12;
    const float* p1 = p0 + 256 * 12;
    #pragma unroll
    for (int t = 0; t < 12; ++t) { l0[t] = p0[t]; l1[t] = p1[t]; }
  }
  if (tid < 96) rh[tid] = rhsS[((size_t)b * 512 + mc * 8) * 12 + tid];
  __syncthreads();

  #pragma unroll
  for (int mm = 0; mm < 8; ++mm) {
    int m = mc * 8 + mm;
    float q0 = beT[m * 512 + tid];
    float q1 = beT[m * 512 + tid + 256];
    const float* rw = &rh[mm * 12];
    #pragma unroll
    for (int t = 0; t < 12; ++t) {
      q0 = fmaf(l0[t], rw[t], q0);
      q1 = fmaf(l1[t], rw[t], q1);
    }
    sL[mm][tid]       = 1.0f / (1.0f + __expf(-q0));
    sL[mm][tid + 256] = 1.0f / (1.0f + __expf(-q1));
  }
  __syncthreads();

  for (int cc = 0; cc < 2; ++cc) {
    int mm = wave + cc * 4;
    int m = mc * 8 + mm;
    int cnt = ccnt[m];
    if (cnt > MAXNZ) cnt = MAXNZ;
    const float4* sw4 = (const float4*)sL[mm];
    const unsigned* cj = colj + m * MAXNZ;

    int e0 = grp;
    for (; e0 + 4 < cnt; e0 += 8) {
      unsigned pk0 = cj[e0], pk1 = cj[e0 + 4];
      int j0 = pk0 & 0xffff, s0 = (int)(pk0 >> 16);
      int j1 = pk1 & 0xffff, s1 = (int)(pk1 >> 16);
      const float4* va = (const float4*)(Ve + (size_t)j0 * 512);
      const float4* vb = (const float4*)(Ve + (size_t)j1 * 512);
      float a = 0.f, c = 0.f;
      #pragma unroll
      for (int i = 0; i < 8; ++i) {
        float4 s4 = sw4[lg + 16 * i];
        float4 v4 = va[lg + 16 * i];
        float4 w4 = vb[lg + 16 * i];
        a = fmaf(v4.x, s4.x, a); a = fmaf(v4.y, s4.y, a);
        a = fmaf(v4.z, s4.z, a); a = fmaf(v4.w, s4.w, a);
        c = fmaf(w4.x, s4.x, c); c = fmaf(w4.y, s4.y, c);
        c = fmaf(w4.z, s4.z, c); c = fmaf(w4.w, s4.w, c);
      }
      #pragma unroll
      for (int off = 8; off; off >>= 1) {
        a += __shfl_xor(a, off, 64);
        c += __shfl_xor(c, off, 64);
      }
      if (lg == 0) {
        evals[((size_t)b * 512 + j0) * MAXNZ + s0] = a;
        evals[((size_t)b * 512 + j1) * MAXNZ + s1] = c;
      }
    }
    if (e0 < cnt) {
      unsigned pk0 = cj[e0];
      int j0 = pk0 & 0xffff, s0 = (int)(pk0 >> 16);
      const float4* va = (const float4*)(Ve + (size_t)j0 * 512);
      float a = 0.f;
      #pragma unroll
      for (int i = 0; i < 8; ++i) {
        float4 s4 = sw4[lg + 16 * i];
        float4 v4 = va[lg + 16 * i];
        a = fmaf(v4.x, s4.x, a); a = fmaf(v4.y, s4.y, a);
        a = fmaf(v4.z, s4.z, a); a = fmaf(v4.w, s4.w, a);
      }
      #pragma unroll
      for (int off = 8; off; off >>= 1) a += __shfl_xor(a, off, 64);
      if (lg == 0) evals[((size_t)b * 512 + j0) * MAXNZ + s0] = a;
    }
  }
}

// ---------------------------------------------------------------------------
// Kernel 6 (v12): wave per (b,j). Phase A = xT bf16 gather + fused softmax.
//   Phase B = MFMA (8x mfma_f32_16x16x32_bf16).
// XCD swizzle: grid = 8192, sbid = (bid&7)*1024 + (bid>>3) bijective.
// ---------------------------------------------------------------------------
__global__ __launch_bounds__(256) void k_out12(
    const unsigned short* __restrict__ xT,
    const int* __restrict__ nnz, const int* __restrict__ cidx,
    const float* __restrict__ evals,
    const unsigned short* __restrict__ KF, const float* __restrict__ bias,
    float* __restrict__ out)
{
  int tid = threadIdx.x;
  int wv = tid >> 6, lane = tid & 63;
  int bid = blockIdx.x;
  int sbid = (bid & 7) * 1024 + (bid >> 3);  // bijective on [0,8192)
  int unit = sbid * 4 + wv;                  // b*512 + j
  int b = unit >> 9, j = unit & 511;

  __shared__ unsigned short convB[4][16][80];  // bf16, row stride 160 B
  __shared__ float valL[4][MAXNZ];
  __shared__ int   idxL[4][MAXNZ];

  int cnt = nnz[j];
  for (int s = lane; s < cnt; s += 64) {
    idxL[wv][s] = cidx[j * MAXNZ + s];
    valL[wv][s] = evals[(size_t)unit * MAXNZ + s];
  }
  // ---- fused masked softmax over this wave's slots (wave-local) ----
  {
    float v0 = lane < cnt        ? valL[wv][lane]      : -__builtin_inff();
    float v1 = (lane + 64) < cnt ? valL[wv][lane + 64] : -__builtin_inff();
    float mx = fmaxf(v0, v1);
    #pragma unroll
    for (int off = 32; off; off >>= 1) mx = fmaxf(mx, __shfl_xor(mx, off, 64));
    float e0 = lane < cnt        ? __expf(v0 - mx) : 0.f;
    float e1 = (lane + 64) < cnt ? __expf(v1 - mx) : 0.f;
    float ssum = wred_sum(e0 + e1);
    float inv = 1.0f / ssum;
    if (lane < cnt)        valL[wv][lane]      = e0 * inv;
    if ((lane + 64) < cnt) valL[wv][lane + 64] = e1 * inv;
  }

  // ---- phase A: bf16 gather from xT (contiguous, imm-offset) ----
  float2 acc[6];
  #pragma unroll
  for (int i = 0; i < 6; ++i) acc[i] = make_float2(0.f, 0.f);

  const unsigned* xb = reinterpret_cast<const unsigned*>(
      xT + (size_t)b * NN * (TT * FF));

  int s = 0;
  for (; s + 1 < cnt; s += 2) {
    int   k0 = idxL[wv][s],     k1 = idxL[wv][s + 1];
    float v0 = valL[wv][s],     v1 = valL[wv][s + 1];
    const unsigned* p0 = xb + k0 * 384 + lane;
    const unsigned* p1 = xb + k1 * 384 + lane;
    unsigned a0 = p0[0],   a1 = p0[64],  a2 = p0[128],
             a3 = p0[192], a4 = p0[256], a5 = p0[320];
    unsigned c0 = p1[0],   c1 = p1[64],  c2 = p1[128],
             c3 = p1[192], c4 = p1[256], c5 = p1[320];
    acc[0].x = fmaf(v0, bflo(a0), acc[0].x); acc[0].y = fmaf(v0, bfhi(a0), acc[0].y);
    acc[1].x = fmaf(v0, bflo(a1), acc[1].x); acc[1].y = fmaf(v0, bfhi(a1), acc[1].y);
    acc[2].x = fmaf(v0, bflo(a2), acc[2].x); acc[2].y = fmaf(v0, bfhi(a2), acc[2].y);
    acc[3].x = fmaf(v0, bflo(a3), acc[3].x); acc[3].y = fmaf(v0, bfhi(a3), acc[3].y);
    acc[4].x = fmaf(v0, bflo(a4), acc[4].x); acc[4].y = fmaf(v0, bfhi(a4), acc[4].y);
    acc[5].x = fmaf(v0, bflo(a5), acc[5].x); acc[5].y = fmaf(v0, bfhi(a5), acc[5].y);
    acc[0].x = fmaf(v1, bflo(c0), acc[0].x); acc[0].y = fmaf(v1, bfhi(c0), acc[0].y);
    acc[1].x = fmaf(v1, bflo(c1), acc[1].x); acc[1].y = fmaf(v1, bfhi(c1), acc[1].y);
    acc[2].x = fmaf(v1, bflo(c2), acc[2].x); acc[2].y = fmaf(v1, bfhi(c2), acc[2].y);
    acc[3].x = fmaf(v1, bflo(c3), acc[3].x); acc[3].y = fmaf(v1, bfhi(c3), acc[3].y);
    acc[4].x = fmaf(v1, bflo(c4), acc[4].x); acc[4].y = fmaf(v1, bfhi(c4), acc[4].y);
    acc[5].x = fmaf(v1, bflo(c5), acc[5].x); acc[5].y = fmaf(v1, bfhi(c5), acc[5].y);
  }
  if (s < cnt) {
    int   k0 = idxL[wv][s];
    float v0 = valL[wv][s];
    const unsigned* p0 = xb + k0 * 384 + lane;
    unsigned a0 = p0[0],   a1 = p0[64],  a2 = p0[128],
             a3 = p0[192], a4 = p0[256], a5 = p0[320];
    acc[0].x = fmaf(v0, bflo(a0), acc[0].x); acc[0].y = fmaf(v0, bfhi(a0), acc[0].y);
    acc[1].x = fmaf(v0, bflo(a1), acc[1].x); acc[1].y = fmaf(v0, bfhi(a1), acc[1].y);
    acc[2].x = fmaf(v0, bflo(a2), acc[2].x); acc[2].y = fmaf(v0, bfhi(a2), acc[2].y);
    acc[3].x = fmaf(v0, bflo(a3), acc[3].x); acc[3].y = fmaf(v0, bfhi(a3), acc[3].y);
    acc[4].x = fmaf(v0, bflo(a4), acc[4].x); acc[4].y = fmaf(v0, bfhi(a4), acc[4].y);
    acc[5].x = fmaf(v0, bflo(a5), acc[5].x); acc[5].y = fmaf(v0, bfhi(a5), acc[5].y);
  }

  // ---- stage conv to LDS as bf16 (acc[i] -> t = 2i+half, f = 2fl,2fl+1) ----
  int half = lane >> 5, fl = lane & 31;
  {
    unsigned short* cb = &convB[wv][0][0];
    #pragma unroll
    for (int i = 0; i < 6; ++i) {
      int t = 2 * i + half;
      __hip_bfloat16 hx = __float2bfloat16(acc[i].x);
      __hip_bfloat16 hy = __float2bfloat16(acc[i].y);
      unsigned pkd = (unsigned)*reinterpret_cast<unsigned short*>(&hx)
                   | ((unsigned)*reinterpret_cast<unsigned short*>(&hy) << 16);
      *reinterpret_cast<unsigned*>(&cb[t * 80 + fl * 2]) = pkd;
    }
  }

  // ---- phase B: 8x MFMA ----
  int arow = lane & 15, agrp = lane >> 4;
  bf16x8 afrag0 = *reinterpret_cast<const bf16x8*>(&convB[wv][arow][agrp * 8]);
  bf16x8 afrag1 = *reinterpret_cast<const bf16x8*>(&convB[wv][arow][32 + agrp * 8]);
  const bf16x8* kf = reinterpret_cast<const bf16x8*>(KF);

  #pragma unroll
  for (int nt = 0; nt < 4; ++nt) {
    f32x4 accT = {0.f, 0.f, 0.f, 0.f};
    accT = __builtin_amdgcn_mfma_f32_16x16x32_bf16(afrag0, kf[(0 * 4 + nt) * 64 + lane], accT, 0, 0, 0);
    accT = __builtin_amdgcn_mfma_f32_16x16x32_bf16(afrag1, kf[(1 * 4 + nt) * 64 + lane], accT, 0, 0, 0);
    int u = nt * 16 + arow;
    float bb = bias[u];
    #pragma unroll
    for (int r = 0; r < 4; ++r) {
      int t = agrp * 4 + r;   // D row = (lane>>4)*4 + reg (HW-verified)
      if (t < 12)
        out[((size_t)(b * TT + t) * NN + j) * UU + u] = accT[r] + bb;
    }
  }
}

// ---------------------------------------------------------------------------
// Kernel 6 fallback (fp32 scalar gather + fused softmax + fmaf phase B)
// ---------------------------------------------------------------------------
__global__ __launch_bounds__(256) void k_out3f(
    const float* __restrict__ x,
    const int* __restrict__ nnz, const int* __restrict__ cidx,
    const float* __restrict__ evals,
    const float* __restrict__ K, const float* __restrict__ bias,
    float* __restrict__ out)
{
  int wv = threadIdx.x >> 6, lane = threadIdx.x & 63;
  int bid = blockIdx.x;
  int sbid = (bid & 7) * 1024 + (bid >> 3);
  int unit = sbid * 4 + wv;
  int b = unit >> 9, j = unit & 511;

  __shared__ float convL[4][12][64];
  __shared__ float valL[4][MAXNZ];
  __shared__ int   idxL[4][MAXNZ];

  int cnt = nnz[j];
  for (int s = lane; s < cnt; s += 64) {
    idxL[wv][s] = cidx[j * MAXNZ + s];
    valL[wv][s] = evals[(size_t)unit * MAXNZ + s];
  }
  {
    float v0 = lane < cnt        ? valL[wv][lane]      : -__builtin_inff();
    float v1 = (lane + 64) < cnt ? valL[wv][lane + 64] : -__builtin_inff();
    float mx = fmaxf(v0, v1);
    #pragma unroll
    for (int off = 32; off; off >>= 1) mx = fmaxf(mx, __shfl_xor(mx, off, 64));
    float e0 = lane < cnt        ? __expf(v0 - mx) : 0.f;
    float e1 = (lane + 64) < cnt ? __expf(v1 - mx) : 0.f;
    float ssum = wred_sum(e0 + e1);
    float inv = 1.0f / ssum;
    if (lane < cnt)        valL[wv][lane]      = e0 * inv;
    if ((lane + 64) < cnt) valL[wv][lane + 64] = e1 * inv;
  }

  float acc[12];
  #pragma unroll
  for (int t = 0; t < 12; ++t) acc[t] = 0.f;

  const float* xb = x + (size_t)b * TT * NN * FF + lane;
  for (int s = 0; s < cnt; ++s) {
    float v = valL[wv][s];
    const float* xk = xb + (size_t)idxL[wv][s] * FF;
    #pragma unroll
    for (int t = 0; t < 12; ++t)
      acc[t] = fmaf(v, xk[(size_t)t * NN * FF], acc[t]);
  }
  #pragma unroll
  for (int t = 0; t < 12; ++t) convL[wv][t][lane] = acc[t];

  float bs = bias[lane];
  float o[12];
  #pragma unroll
  for (int t = 0; t < 12; ++t) o[t] = bs;
  __syncthreads();

  #pragma unroll
  for (int ft = 0; ft < 4; ++ft) {
    float kc[16];
    #pragma unroll
    for (int i = 0; i < 16; ++i) kc[i] = K[(ft * 16 + i) * 64 + lane];
    #pragma unroll
    for (int t = 0; t < 12; ++t) {
      const float4* cv = (const float4*)&convL[wv][t][ft * 16];
      float4 c0 = cv[0], c1 = cv[1], c2 = cv[2], c3 = cv[3];
      float o_ = o[t];
      o_ = fmaf(c0.x, kc[0],  o_); o_ = fmaf(c0.y, kc[1],  o_);
      o_ = fmaf(c0.z, kc[2],  o_); o_ = fmaf(c0.w, kc[3],  o_);
      o_ = fmaf(c1.x, kc[4],  o_); o_ = fmaf(c1.y, kc[5],  o_);
      o_ = fmaf(c1.z, kc[6],  o_); o_ = fmaf(c1.w, kc[7],  o_);
      o_ = fmaf(c2.x, kc[8],  o_); o_ = fmaf(c2.y, kc[9],  o_);
      o_ = fmaf(c2.z, kc[10], o_); o_ = fmaf(c2.w, kc[11], o_);
      o_ = fmaf(c3.x, kc[12], o_); o_ = fmaf(c3.y, kc[13], o_);
      o_ = fmaf(c3.z, kc[14], o_); o_ = fmaf(c3.w, kc[15], o_);
      o[t] = o_;
    }
  }

  #pragma unroll
  for (int t = 0; t < 12; ++t)
    out[((size_t)(b * TT + t) * NN + j) * UU + lane] = o[t];
}

// ---------------------------------------------------------------------------
extern "C" void kernel_launch(void* const* d_in, const int* in_sizes, int n_in,
                              void* d_out, int out_size, void* d_ws, size_t ws_size,
                              hipStream_t stream)
{
  const float* x    = (const float*)d_in[0];  // (B,T,N,F)
  const float* A    = (const float*)d_in[1];  // (N,N)
  const float* W1   = (const float*)d_in[2];  // (T,1)
  const float* W2   = (const float*)d_in[3];  // (F,T)
  const float* W3   = (const float*)d_in[4];  // (F,1)
  const float* Ve   = (const float*)d_in[5];  // (N,N)
  const float* be   = (const float*)d_in[6];  // (N,N)
  const float* K    = (const float*)d_in[7];  // (F,U)
  const float* bias = (const float*)d_in[8];  // (U,)
  float* out = (float*)d_out;

  char* ws = (char*)d_ws;
  float* lhs   = (float*)ws + OF_LHS;
  float* rhsS  = (float*)ws + OF_RHS;
  float* beT   = (float*)ws + OF_BET;
  float* evals = (float*)ws + OF_EVALS;
  int*      nnz  = (int*)(ws + OB_NNZ);
  int*      cidx = (int*)(ws + OB_CIDX);
  int*      ccnt = (int*)(ws + OB_CCNT);
  unsigned* colj = (unsigned*)(ws + OB_COLJ);
  unsigned short* xT  = (unsigned short*)(ws + OB_XT);
  unsigned short* KF  = (unsigned short*)(ws + OB_KF);
  unsigned short* VeB = (unsigned short*)(ws + OB_VEB);

  const bool use_xt  = ws_size >= OB_KF + KF_BYTES;
  const bool use_veb = ws_size >= OB_VEB + VEB_BYTES;

  hipMemsetAsync(ccnt, 0, NN * sizeof(int), stream);

  // 1. lhs / rhs (+ transposed bf16 copy of x)
  k_lhs_rhs<<<dim3(BB * NN / 4), dim3(256), 0, stream>>>(
      x, W1, W2, W3, lhs, rhsS, use_xt ? xT : nullptr);
  // 2. transpose be (+ KF + VeB builds)
  k_transpose<<<dim3(NN * NN / 256 + 1 + (use_veb ? 32 : 0)), dim3(256), 0, stream>>>(
      be, beT, K, use_xt ? KF : nullptr, Ve, use_veb ? VeB : nullptr);
  // 3. row index lists
  k_build_idx<<<dim3(NN), dim3(64), 0, stream>>>(A, nnz, cidx);
  // 4. column lists
  k_build_col<<<dim3(NN), dim3(64), 0, stream>>>(nnz, cidx, ccnt, colj);
  // 5. product + sigmoid + masked E (v6: bf16 Ve, half L2 bytes)
  if (use_veb)
    k_product_E6<<<dim3(BB, NN / 8), dim3(256), 0, stream>>>(lhs, rhsS, beT, VeB, ccnt, colj, evals);
  else
    k_product_E5<<<dim3(BB, NN / 8), dim3(256), 0, stream>>>(lhs, rhsS, beT, Ve, ccnt, colj, evals);
  // 6. sparse conv + fused softmax + MFMA output GEMM
  if (use_xt)
    k_out12<<<dim3(BB * NN / 4), dim3(256), 0, stream>>>(xT, nnz, cidx, evals, KF, bias, out);
  else
    k_out3f<<<dim3(BB * NN / 4), dim3(256), 0, stream>>>(x, nnz, cidx, evals, K, bias, out);
}

// Round 21
// 181.505 us; speedup vs baseline: 1.2322x; 1.2009x over previous
//
#include <hip/hip_runtime.h>
#include <hip/hip_bf16.h>
#include <cstdint>

// Problem constants
constexpr int BB = 64;    // batch
constexpr int TT = 12;    // time
constexpr int NN = 512;   // nodes
constexpr int FF = 64;    // features
constexpr int UU = 64;    // units
constexpr int MAXNZ = 128;

// ---------------------------------------------------------------------------
// Workspace layout (bytes):
//   floats: lhs 0 / rhs 393216f / beT 786432f / evals 1048576f
//   ints:   nnz 20971520 / cidx 20973568 / ccnt 21235712 / colj 21237760
//   xT (B,N,T,F) bf16 : 21516288, 50331648 B
//   KF  : 71847936, 8192 B
//   VeB : 71856128, 524288 B
//   ST (B,N,N) bf16 [b][m][k] : 72380416, 33554432 B  -> ends 105934848
// ---------------------------------------------------------------------------
constexpr size_t OF_LHS   = 0;
constexpr size_t OF_RHS   = 393216;
constexpr size_t OF_BET   = 786432;
constexpr size_t OF_EVALS = 1048576;
constexpr size_t OB_NNZ   = 20971520;
constexpr size_t OB_CIDX  = 20973568;
constexpr size_t OB_CCNT  = 21235712;
constexpr size_t OB_COLJ  = 21237760;
constexpr size_t OB_XT    = 21516288;
constexpr size_t XT_BYTES = (size_t)BB * NN * TT * FF * 2;  // 50331648
constexpr size_t OB_KF    = 71847936;
constexpr size_t KF_BYTES = 8 * 64 * 8 * 2;                 // 8192
constexpr size_t OB_VEB   = 71856128;
constexpr size_t VEB_BYTES = (size_t)NN * NN * 2;           // 524288
constexpr size_t OB_ST    = 72380416;
constexpr size_t ST_BYTES = (size_t)BB * NN * NN * 2;       // 33554432

typedef __attribute__((ext_vector_type(8))) short bf16x8;   // 8 bf16 = 4 VGPRs
typedef __attribute__((ext_vector_type(4))) float f32x4;

__device__ __forceinline__ float wred_sum(float v) {
  #pragma unroll
  for (int off = 32; off; off >>= 1) v += __shfl_xor(v, off, 64);
  return v;
}

__device__ __forceinline__ float bflo(unsigned u) {
  return __uint_as_float(u << 16);
}
__device__ __forceinline__ float bfhi(unsigned u) {
  return __uint_as_float(u & 0xFFFF0000u);
}

// ---------------------------------------------------------------------------
// Kernel 1: lhs/rhs reductions; also writes xT[b][n][t][f] bf16
// ---------------------------------------------------------------------------
__global__ __launch_bounds__(256) void k_lhs_rhs(
    const float* __restrict__ x, const float* __restrict__ W1,
    const float* __restrict__ W2, const float* __restrict__ W3,
    float* __restrict__ lhs, float* __restrict__ rhsS,
    unsigned short* __restrict__ xT)   // may be null
{
  int unit = blockIdx.x * 4 + (threadIdx.x >> 6);   // b*512 + n
  int lane = threadIdx.x & 63;
  int b = unit >> 9, n = unit & 511;

  const float* xb = x + ((size_t)b * TT * NN + n) * FF + lane;
  float xv[12];
  #pragma unroll
  for (int t = 0; t < 12; ++t) xv[t] = xb[(size_t)t * NN * FF];

  if (xT) {
    unsigned short* xo = xT + (size_t)unit * (TT * FF) + lane;
    #pragma unroll
    for (int t = 0; t < 12; ++t) {
      __hip_bfloat16 h = __float2bfloat16(xv[t]);   // RTNE
      xo[t * FF] = *reinterpret_cast<unsigned short*>(&h);
    }
  }

  float r1 = 0.f;
  #pragma unroll
  for (int t = 0; t < 12; ++t) r1 += xv[t] * W1[t];

  float w3 = W3[lane];

  float myl = 0.f, myr = 0.f;
  #pragma unroll
  for (int t = 0; t < 12; ++t) {
    float a = r1 * W2[lane * 12 + t];
    float c = xv[t] * w3;
    a = wred_sum(a);
    c = wred_sum(c);
    if (lane == t) { myl = a; myr = c; }
  }
  if (lane < 12) {
    lhs[(size_t)unit * 12 + lane]  = myl;
    rhsS[(size_t)unit * 12 + lane] = myr;
  }
}

// ---------------------------------------------------------------------------
// Kernel 2: beT[m,k] = be[k,m]; block 1024 builds KF; blocks 1025+ build VeB.
// ---------------------------------------------------------------------------
__global__ __launch_bounds__(256) void k_transpose(
    const float* __restrict__ be, float* __restrict__ beT,
    const float* __restrict__ K, unsigned short* __restrict__ KF,
    const float* __restrict__ Ve, unsigned short* __restrict__ VeB)
{
  int bid = blockIdx.x;
  if (bid < NN * NN / 256) {
    int i = bid * 256 + threadIdx.x;  // 262144 total
    int k = i >> 9, m = i & 511;
    beT[m * 512 + k] = be[i];
    return;
  }
  if (bid == NN * NN / 256) {
    if (KF) {
      for (int idx = threadIdx.x; idx < 512; idx += 256) {
        int frag = idx >> 6, l = idx & 63;
        int kk = frag >> 2, nt = frag & 3;
        int u = nt * 16 + (l & 15);
        unsigned short* dst = KF + (size_t)idx * 8;
        for (int e = 0; e < 8; ++e) {
          int f = kk * 32 + (l >> 4) * 8 + e;
          __hip_bfloat16 h = __float2bfloat16(K[f * 64 + u]);
          dst[e] = *reinterpret_cast<unsigned short*>(&h);
        }
      }
    }
    return;
  }
  if (VeB) {
    int b2 = bid - (NN * NN / 256 + 1);   // 0..31
    #pragma unroll
    for (int i = 0; i < 32; ++i) {
      int idx = b2 * 8192 + i * 256 + threadIdx.x;
      __hip_bfloat16 h = __float2bfloat16(Ve[idx]);
      VeB[idx] = *reinterpret_cast<unsigned short*>(&h);
    }
  }
}

// ---------------------------------------------------------------------------
// Kernel 3: row-wise compaction of mask A (deterministic, ordered by m)
// ---------------------------------------------------------------------------
__global__ void k_build_idx(const float* __restrict__ A,
                            int* __restrict__ nnz, int* __restrict__ cidx)
{
  int j = blockIdx.x;
  int lane = threadIdx.x;  // 64 threads
  unsigned long long lt = (1ull << lane) - 1ull;
  int base = 0;
  for (int c = 0; c < 8; ++c) {
    int m = c * 64 + lane;
    bool p = A[(size_t)j * 512 + m] > 0.5f;
    unsigned long long mask = __ballot(p);
    int pos = base + __popcll(mask & lt);
    if (p && pos < MAXNZ) cidx[j * MAXNZ + pos] = m;
    base += __popcll(mask);
  }
  if (lane == 0) nnz[j] = base > MAXNZ ? MAXNZ : base;
}

// ---------------------------------------------------------------------------
// Kernel 4: column lists
// ---------------------------------------------------------------------------
__global__ void k_build_col(const int* __restrict__ nnz, const int* __restrict__ cidx,
                            int* __restrict__ ccnt, unsigned* __restrict__ colj)
{
  int j = blockIdx.x;
  int lane = threadIdx.x;
  int cnt = nnz[j];
  for (int s = lane; s < cnt; s += 64) {
    int m = cidx[j * MAXNZ + s];
    int pos = atomicAdd(&ccnt[m], 1);
    if (pos < MAXNZ) colj[m * MAXNZ + pos] = (unsigned)j | ((unsigned)s << 16);
  }
}

// ---------------------------------------------------------------------------
// Kernel 5a (MFMA path): streaming sigmoid -> ST[b][m][k] bf16.
//   Register lhs (E5-proven), no sL tile, coalesced 2B stores.
// ---------------------------------------------------------------------------
__global__ __launch_bounds__(256) void k_sigmoid2(
    const float* __restrict__ lhs, const float* __restrict__ rhsS,
    const float* __restrict__ beT, unsigned short* __restrict__ ST)
{
  int b  = blockIdx.x;   // 0..63
  int mc = blockIdx.y;   // 0..31 (16 m's)

  __shared__ float rh[16 * 12];
  int tid = threadIdx.x;

  float l0[12], l1[12];
  {
    const float* p0 = lhs + ((size_t)b * 512 + tid) * 12;
    const float* p1 = p0 + 256 * 12;
    #pragma unroll
    for (int t = 0; t < 12; ++t) { l0[t] = p0[t]; l1[t] = p1[t]; }
  }
  if (tid < 192) rh[tid] = rhsS[((size_t)b * 512 + mc * 16) * 12 + tid];
  __syncthreads();

  #pragma unroll 4
  for (int mm = 0; mm < 16; ++mm) {
    int m = mc * 16 + mm;
    float q0 = beT[m * 512 + tid];
    float q1 = beT[m * 512 + tid + 256];
    const float* rw = &rh[mm * 12];
    #pragma unroll
    for (int t = 0; t < 12; ++t) {
      q0 = fmaf(l0[t], rw[t], q0);
      q1 = fmaf(l1[t], rw[t], q1);
    }
    float s0 = 1.0f / (1.0f + __expf(-q0));
    float s1 = 1.0f / (1.0f + __expf(-q1));
    __hip_bfloat16 h0 = __float2bfloat16(s0);
    __hip_bfloat16 h1 = __float2bfloat16(s1);
    unsigned short* dst = ST + ((size_t)(b * NN + m)) * NN;
    dst[tid]       = *reinterpret_cast<unsigned short*>(&h0);
    dst[tid + 256] = *reinterpret_cast<unsigned short*>(&h1);
  }
}

// ---------------------------------------------------------------------------
// Kernel 5b (MFMA path): E[entries(m), b] = Ve[entries,:] @ S[:,m,b].
//   Block = column m (512 blocks, 4 waves; wave w owns b-tile w*16..+16).
//   B-frags: 16 k-steps of S from ST (dwordx4, register-resident, 64 VGPR).
//   A: 32 Ve entry-rows gathered to LDS VeL[32][520] (pad -> 2-way banks).
//   2 j-tiles x 16 k-steps of mfma_f32_16x16x32_bf16 per wave per chunk.
//   A/B share k-map (l>>4)*8+e (k-permutation invariance, as k_out12).
//   D: col=lane&15 = b_local, row=(lane>>4)*4+reg = entry (HW-verified map);
//   scatter dword writes to evals[b][j][slot].
// ---------------------------------------------------------------------------
__global__ __launch_bounds__(256) void k_E_mfma(
    const unsigned short* __restrict__ ST, const unsigned short* __restrict__ VeB,
    const int* __restrict__ ccnt, const unsigned* __restrict__ colj,
    float* __restrict__ evals)
{
  int m = blockIdx.x;            // 0..511
  int tid = threadIdx.x;
  int wv = tid >> 6, lane = tid & 63;
  int arow = lane & 15, kgrp = lane >> 4;

  __shared__ unsigned short VeL[32][520];   // 33.3 KB (row stride 1040 B)
  __shared__ unsigned entL[MAXNZ];

  int cnt = ccnt[m];
  if (cnt > MAXNZ) cnt = MAXNZ;
  for (int e = tid; e < cnt; e += 256) entL[e] = colj[m * MAXNZ + e];

  // B-fragments (register-resident): lane holds S[k=kgrp*8+kk*32 ..+8][b]
  bf16x8 bfrag[16];
  {
    const unsigned short* sb =
        ST + ((size_t)((wv * 16 + arow) * NN + m)) * NN + kgrp * 8;
    #pragma unroll
    for (int kk = 0; kk < 16; ++kk)
      bfrag[kk] = *reinterpret_cast<const bf16x8*>(sb + kk * 32);
  }

  for (int c0 = 0; c0 < cnt; c0 += 32) {
    __syncthreads();   // entL ready (1st iter); VeL consumed (later iters)
    // stage 32 Ve rows (zero-pad past cnt); 8 threads/row, 64B-interleaved
    {
      int r = tid >> 3, seg = tid & 7;
      int e = c0 + r;
      uint2* dst = reinterpret_cast<uint2*>(&VeL[r][0]);
      if (e < cnt) {
        unsigned jrow = entL[e] & 0xffffu;
        const uint2* src = reinterpret_cast<const uint2*>(VeB + (size_t)jrow * 512);
        #pragma unroll
        for (int i = 0; i < 16; ++i) dst[seg + 8 * i] = src[seg + 8 * i];
      } else {
        uint2 z = make_uint2(0u, 0u);
        #pragma unroll
        for (int i = 0; i < 16; ++i) dst[seg + 8 * i] = z;
      }
    }
    __syncthreads();

    int b = wv * 16 + arow;
    #pragma unroll
    for (int jt = 0; jt < 2; ++jt) {
      f32x4 acc = {0.f, 0.f, 0.f, 0.f};
      #pragma unroll
      for (int kk = 0; kk < 16; ++kk) {
        bf16x8 af = *reinterpret_cast<const bf16x8*>(
            &VeL[jt * 16 + arow][kgrp * 8 + kk * 32]);
        acc = __builtin_amdgcn_mfma_f32_16x16x32_bf16(af, bfrag[kk], acc, 0, 0, 0);
      }
      #pragma unroll
      for (int r = 0; r < 4; ++r) {
        int e = c0 + jt * 16 + kgrp * 4 + r;
        if (e < cnt) {
          unsigned pk = entL[e];
          int j = pk & 0xffff, slot = (int)(pk >> 16);
          evals[((size_t)b * 512 + j) * MAXNZ + slot] = acc[r];
        }
      }
    }
  }
}

// ---------------------------------------------------------------------------
// Kernel 5 fallback (v6): E5 structure, bf16 Ve reads (R20-measured 84us)
// ---------------------------------------------------------------------------
__global__ __launch_bounds__(256) void k_product_E6(
    const float* __restrict__ lhs, const float* __restrict__ rhsS,
    const float* __restrict__ beT, const unsigned short* __restrict__ VeB,
    const int* __restrict__ ccnt, const unsigned* __restrict__ colj,
    float* __restrict__ evals)
{
  int b  = blockIdx.x;
  int mc = blockIdx.y;

  __shared__ __align__(16) float sL[8][512];
  __shared__ float rh[8 * 12];

  int tid = threadIdx.x;
  int wave = tid >> 6, lane = tid & 63;
  int grp = lane >> 4, lg = lane & 15;

  float l0[12], l1[12];
  {
    const float* p0 = lhs + ((size_t)b * 512 + tid) * 12;
    const float* p1 = p0 + 256 * 12;
    #pragma unroll
    for (int t = 0; t < 12; ++t) { l0[t] = p0[t]; l1[t] = p1[t]; }
  }
  if (tid < 96) rh[tid] = rhsS[((size_t)b * 512 + mc * 8) * 12 + tid];
  __syncthreads();

  #pragma unroll
  for (int mm = 0; mm < 8; ++mm) {
    int m = mc * 8 + mm;
    float q0 = beT[m * 512 + tid];
    float q1 = beT[m * 512 + tid + 256];
    const float* rw = &rh[mm * 12];
    #pragma unroll
    for (int t = 0; t < 12; ++t) {
      q0 = fmaf(l0[t], rw[t], q0);
      q1 = fmaf(l1[t], rw[t], q1);
    }
    sL[mm][tid]       = 1.0f / (1.0f + __expf(-q0));
    sL[mm][tid + 256] = 1.0f / (1.0f + __expf(-q1));
  }
  __syncthreads();

  for (int cc = 0; cc < 2; ++cc) {
    int mm = wave + cc * 4;
    int m = mc * 8 + mm;
    int cnt = ccnt[m];
    if (cnt > MAXNZ) cnt = MAXNZ;
    const float4* sw4 = (const float4*)sL[mm];
    const unsigned* cj = colj + m * MAXNZ;

    int e0 = grp;
    for (; e0 + 4 < cnt; e0 += 8) {
      unsigned pk0 = cj[e0], pk1 = cj[e0 + 4];
      int j0 = pk0 & 0xffff, s0 = (int)(pk0 >> 16);
      int j1 = pk1 & 0xffff, s1 = (int)(pk1 >> 16);
      const uint2* va = (const uint2*)(VeB + (size_t)j0 * 512);
      const uint2* vb = (const uint2*)(VeB + (size_t)j1 * 512);
      float a = 0.f, c = 0.f;
      #pragma unroll
      for (int i = 0; i < 8; ++i) {
        float4 s4 = sw4[lg + 16 * i];
        uint2  u0 = va[lg + 16 * i];
        uint2  u1 = vb[lg + 16 * i];
        a = fmaf(bflo(u0.x), s4.x, a); a = fmaf(bfhi(u0.x), s4.y, a);
        a = fmaf(bflo(u0.y), s4.z, a); a = fmaf(bfhi(u0.y), s4.w, a);
        c = fmaf(bflo(u1.x), s4.x, c); c = fmaf(bfhi(u1.x), s4.y, c);
        c = fmaf(bflo(u1.y), s4.z, c); c = fmaf(bfhi(u1.y), s4.w, c);
      }
      #pragma unroll
      for (int off = 8; off; off >>= 1) {
        a += __shfl_xor(a, off, 64);
        c += __shfl_xor(c, off, 64);
      }
      if (lg == 0) {
        evals[((size_t)b * 512 + j0) * MAXNZ + s0] = a;
        evals[((size_t)b * 512 + j1) * MAXNZ + s1] = c;
      }
    }
    if (e0 < cnt) {
      unsigned pk0 = cj[e0];
      int j0 = pk0 & 0xffff, s0 = (int)(pk0 >> 16);
      const uint2* va = (const uint2*)(VeB + (size_t)j0 * 512);
      float a = 0.f;
      #pragma unroll
      for (int i = 0; i < 8; ++i) {
        float4 s4 = sw4[lg + 16 * i];
        uint2  u0 = va[lg + 16 * i];
        a = fmaf(bflo(u0.x), s4.x, a); a = fmaf(bfhi(u0.x), s4.y, a);
        a = fmaf(bflo(u0.y), s4.z, a); a = fmaf(bfhi(u0.y), s4.w, a);
      }
      #pragma unroll
      for (int off = 8; off; off >>= 1) a += __shfl_xor(a, off, 64);
      if (lg == 0) evals[((size_t)b * 512 + j0) * MAXNZ + s0] = a;
    }
  }
}

// ---------------------------------------------------------------------------
// Kernel 5 fallback (fp32 Ve, E5 structure) — if ws too small for VeB
// ---------------------------------------------------------------------------
__global__ __launch_bounds__(256) void k_product_E5(
    const float* __restrict__ lhs, const float* __restrict__ rhsS,
    const float* __restrict__ beT, const float* __restrict__ Ve,
    const int* __restrict__ ccnt, const unsigned* __restrict__ colj,
    float* __restrict__ evals)
{
  int b  = blockIdx.x;
  int mc = blockIdx.y;

  __shared__ __align__(16) float sL[8][512];
  __shared__ float rh[8 * 12];

  int tid = threadIdx.x;
  int wave = tid >> 6, lane = tid & 63;
  int grp = lane >> 4, lg = lane & 15;

  float l0[12], l1[12];
  {
    const float* p0 = lhs + ((size_t)b * 512 + tid) * 12;
    const float* p1 = p0 + 256 * 12;
    #pragma unroll
    for (int t = 0; t < 12; ++t) { l0[t] = p0[t]; l1[t] = p1[t]; }
  }
  if (tid < 96) rh[tid] = rhsS[((size_t)b * 512 + mc * 8) * 12 + tid];
  __syncthreads();

  #pragma unroll
  for (int mm = 0; mm < 8; ++mm) {
    int m = mc * 8 + mm;
    float q0 = beT[m * 512 + tid];
    float q1 = beT[m * 512 + tid + 256];
    const float* rw = &rh[mm * 12];
    #pragma unroll
    for (int t = 0; t < 12; ++t) {
      q0 = fmaf(l0[t], rw[t], q0);
      q1 = fmaf(l1[t], rw[t], q1);
    }
    sL[mm][tid]       = 1.0f / (1.0f + __expf(-q0));
    sL[mm][tid + 256] = 1.0f / (1.0f + __expf(-q1));
  }
  __syncthreads();

  for (int cc = 0; cc < 2; ++cc) {
    int mm = wave + cc * 4;
    int m = mc * 8 + mm;
    int cnt = ccnt[m];
    if (cnt > MAXNZ) cnt = MAXNZ;
    const float4* sw4 = (const float4*)sL[mm];
    const unsigned* cj = colj + m * MAXNZ;

    int e0 = grp;
    for (; e0 + 4 < cnt; e0 += 8) {
      unsigned pk0 = cj[e0], pk1 = cj[e0 + 4];
      int j0 = pk0 & 0xffff, s0 = (int)(pk0 >> 16);
      int j1 = pk1 & 0xffff, s1 = (int)(pk1 >> 16);
      const float4* va = (const float4*)(Ve + (size_t)j0 * 512);
      const float4* vb = (const float4*)(Ve + (size_t)j1 * 512);
      float a = 0.f, c = 0.f;
      #pragma unroll
      for (int i = 0; i < 8; ++i) {
        float4 s4 = sw4[lg + 16 * i];
        float4 v4 = va[lg + 16 * i];
        float4 w4 = vb[lg + 16 * i];
        a = fmaf(v4.x, s4.x, a); a = fmaf(v4.y, s4.y, a);
        a = fmaf(v4.z, s4.z, a); a = fmaf(v4.w, s4.w, a);
        c = fmaf(w4.x, s4.x, c); c = fmaf(w4.y, s4.y, c);
        c = fmaf(w4.z, s4.z, c); c = fmaf(w4.w, s4.w, c);
      }
      #pragma unroll
      for (int off = 8; off; off >>= 1) {
        a += __shfl_xor(a, off, 64);
        c += __shfl_xor(c, off, 64);
      }
      if (lg == 0) {
        evals[((size_t)b * 512 + j0) * MAXNZ + s0] = a;
        evals[((size_t)b * 512 + j1) * MAXNZ + s1] = c;
      }
    }
    if (e0 < cnt) {
      unsigned pk0 = cj[e0];
      int j0 = pk0 & 0xffff, s0 = (int)(pk0 >> 16);
      const float4* va = (const float4*)(Ve + (size_t)j0 * 512);
      float a = 0.f;
      #pragma unroll
      for (int i = 0; i < 8; ++i) {
        float4 s4 = sw4[lg + 16 * i];
        float4 v4 = va[lg + 16 * i];
        a = fmaf(v4.x, s4.x, a); a = fmaf(v4.y, s4.y, a);
        a = fmaf(v4.z, s4.z, a); a = fmaf(v4.w, s4.w, a);
      }
      #pragma unroll
      for (int off = 8; off; off >>= 1) a += __shfl_xor(a, off, 64);
      if (lg == 0) evals[((size_t)b * 512 + j0) * MAXNZ + s0] = a;
    }
  }
}

// ---------------------------------------------------------------------------
// Kernel 6 (v12): wave per (b,j). Phase A = xT bf16 gather + fused softmax.
//   Phase B = MFMA (8x mfma_f32_16x16x32_bf16).
// XCD swizzle: grid = 8192, sbid = (bid&7)*1024 + (bid>>3) bijective.
// ---------------------------------------------------------------------------
__global__ __launch_bounds__(256) void k_out12(
    const unsigned short* __restrict__ xT,
    const int* __restrict__ nnz, const int* __restrict__ cidx,
    const float* __restrict__ evals,
    const unsigned short* __restrict__ KF, const float* __restrict__ bias,
    float* __restrict__ out)
{
  int tid = threadIdx.x;
  int wv = tid >> 6, lane = tid & 63;
  int bid = blockIdx.x;
  int sbid = (bid & 7) * 1024 + (bid >> 3);  // bijective on [0,8192)
  int unit = sbid * 4 + wv;                  // b*512 + j
  int b = unit >> 9, j = unit & 511;

  __shared__ unsigned short convB[4][16][80];  // bf16, row stride 160 B
  __shared__ float valL[4][MAXNZ];
  __shared__ int   idxL[4][MAXNZ];

  int cnt = nnz[j];
  for (int s = lane; s < cnt; s += 64) {
    idxL[wv][s] = cidx[j * MAXNZ + s];
    valL[wv][s] = evals[(size_t)unit * MAXNZ + s];
  }
  // ---- fused masked softmax over this wave's slots (wave-local) ----
  {
    float v0 = lane < cnt        ? valL[wv][lane]      : -__builtin_inff();
    float v1 = (lane + 64) < cnt ? valL[wv][lane + 64] : -__builtin_inff();
    float mx = fmaxf(v0, v1);
    #pragma unroll
    for (int off = 32; off; off >>= 1) mx = fmaxf(mx, __shfl_xor(mx, off, 64));
    float e0 = lane < cnt        ? __expf(v0 - mx) : 0.f;
    float e1 = (lane + 64) < cnt ? __expf(v1 - mx) : 0.f;
    float ssum = wred_sum(e0 + e1);
    float inv = 1.0f / ssum;
    if (lane < cnt)        valL[wv][lane]      = e0 * inv;
    if ((lane + 64) < cnt) valL[wv][lane + 64] = e1 * inv;
  }

  // ---- phase A: bf16 gather from xT (contiguous, imm-offset) ----
  float2 acc[6];
  #pragma unroll
  for (int i = 0; i < 6; ++i) acc[i] = make_float2(0.f, 0.f);

  const unsigned* xb = reinterpret_cast<const unsigned*>(
      xT + (size_t)b * NN * (TT * FF));

  int s = 0;
  for (; s + 1 < cnt; s += 2) {
    int   k0 = idxL[wv][s],     k1 = idxL[wv][s + 1];
    float v0 = valL[wv][s],     v1 = valL[wv][s + 1];
    const unsigned* p0 = xb + k0 * 384 + lane;
    const unsigned* p1 = xb + k1 * 384 + lane;
    unsigned a0 = p0[0],   a1 = p0[64],  a2 = p0[128],
             a3 = p0[192], a4 = p0[256], a5 = p0[320];
    unsigned c0 = p1[0],   c1 = p1[64],  c2 = p1[128],
             c3 = p1[192], c4 = p1[256], c5 = p1[320];
    acc[0].x = fmaf(v0, bflo(a0), acc[0].x); acc[0].y = fmaf(v0, bfhi(a0), acc[0].y);
    acc[1].x = fmaf(v0, bflo(a1), acc[1].x); acc[1].y = fmaf(v0, bfhi(a1), acc[1].y);
    acc[2].x = fmaf(v0, bflo(a2), acc[2].x); acc[2].y = fmaf(v0, bfhi(a2), acc[2].y);
    acc[3].x = fmaf(v0, bflo(a3), acc[3].x); acc[3].y = fmaf(v0, bfhi(a3), acc[3].y);
    acc[4].x = fmaf(v0, bflo(a4), acc[4].x); acc[4].y = fmaf(v0, bfhi(a4), acc[4].y);
    acc[5].x = fmaf(v0, bflo(a5), acc[5].x); acc[5].y = fmaf(v0, bfhi(a5), acc[5].y);
    acc[0].x = fmaf(v1, bflo(c0), acc[0].x); acc[0].y = fmaf(v1, bfhi(c0), acc[0].y);
    acc[1].x = fmaf(v1, bflo(c1), acc[1].x); acc[1].y = fmaf(v1, bfhi(c1), acc[1].y);
    acc[2].x = fmaf(v1, bflo(c2), acc[2].x); acc[2].y = fmaf(v1, bfhi(c2), acc[2].y);
    acc[3].x = fmaf(v1, bflo(c3), acc[3].x); acc[3].y = fmaf(v1, bfhi(c3), acc[3].y);
    acc[4].x = fmaf(v1, bflo(c4), acc[4].x); acc[4].y = fmaf(v1, bfhi(c4), acc[4].y);
    acc[5].x = fmaf(v1, bflo(c5), acc[5].x); acc[5].y = fmaf(v1, bfhi(c5), acc[5].y);
  }
  if (s < cnt) {
    int   k0 = idxL[wv][s];
    float v0 = valL[wv][s];
    const unsigned* p0 = xb + k0 * 384 + lane;
    unsigned a0 = p0[0],   a1 = p0[64],  a2 = p0[128],
             a3 = p0[192], a4 = p0[256], a5 = p0[320];
    acc[0].x = fmaf(v0, bflo(a0), acc[0].x); acc[0].y = fmaf(v0, bfhi(a0), acc[0].y);
    acc[1].x = fmaf(v0, bflo(a1), acc[1].x); acc[1].y = fmaf(v0, bfhi(a1), acc[1].y);
    acc[2].x = fmaf(v0, bflo(a2), acc[2].x); acc[2].y = fmaf(v0, bfhi(a2), acc[2].y);
    acc[3].x = fmaf(v0, bflo(a3), acc[3].x); acc[3].y = fmaf(v0, bfhi(a3), acc[3].y);
    acc[4].x = fmaf(v0, bflo(a4), acc[4].x); acc[4].y = fmaf(v0, bfhi(a4), acc[4].y);
    acc[5].x = fmaf(v0, bflo(a5), acc[5].x); acc[5].y = fmaf(v0, bfhi(a5), acc[5].y);
  }

  // ---- stage conv to LDS as bf16 (acc[i] -> t = 2i+half, f = 2fl,2fl+1) ----
  int half = lane >> 5, fl = lane & 31;
  {
    unsigned short* cb = &convB[wv][0][0];
    #pragma unroll
    for (int i = 0; i < 6; ++i) {
      int t = 2 * i + half;
      __hip_bfloat16 hx = __float2bfloat16(acc[i].x);
      __hip_bfloat16 hy = __float2bfloat16(acc[i].y);
      unsigned pkd = (unsigned)*reinterpret_cast<unsigned short*>(&hx)
                   | ((unsigned)*reinterpret_cast<unsigned short*>(&hy) << 16);
      *reinterpret_cast<unsigned*>(&cb[t * 80 + fl * 2]) = pkd;
    }
  }

  // ---- phase B: 8x MFMA ----
  int arow = lane & 15, agrp = lane >> 4;
  bf16x8 afrag0 = *reinterpret_cast<const bf16x8*>(&convB[wv][arow][agrp * 8]);
  bf16x8 afrag1 = *reinterpret_cast<const bf16x8*>(&convB[wv][arow][32 + agrp * 8]);
  const bf16x8* kf = reinterpret_cast<const bf16x8*>(KF);

  #pragma unroll
  for (int nt = 0; nt < 4; ++nt) {
    f32x4 accT = {0.f, 0.f, 0.f, 0.f};
    accT = __builtin_amdgcn_mfma_f32_16x16x32_bf16(afrag0, kf[(0 * 4 + nt) * 64 + lane], accT, 0, 0, 0);
    accT = __builtin_amdgcn_mfma_f32_16x16x32_bf16(afrag1, kf[(1 * 4 + nt) * 64 + lane], accT, 0, 0, 0);
    int u = nt * 16 + arow;
    float bb = bias[u];
    #pragma unroll
    for (int r = 0; r < 4; ++r) {
      int t = agrp * 4 + r;   // D row = (lane>>4)*4 + reg (HW-verified)
      if (t < 12)
        out[((size_t)(b * TT + t) * NN + j) * UU + u] = accT[r] + bb;
    }
  }
}

// ---------------------------------------------------------------------------
// Kernel 6 fallback (fp32 scalar gather + fused softmax + fmaf phase B)
// ---------------------------------------------------------------------------
__global__ __launch_bounds__(256) void k_out3f(
    const float* __restrict__ x,
    const int* __restrict__ nnz, const int* __restrict__ cidx,
    const float* __restrict__ evals,
    const float* __restrict__ K, const float* __restrict__ bias,
    float* __restrict__ out)
{
  int wv = threadIdx.x >> 6, lane = threadIdx.x & 63;
  int bid = blockIdx.x;
  int sbid = (bid & 7) * 1024 + (bid >> 3);
  int unit = sbid * 4 + wv;
  int b = unit >> 9, j = unit & 511;

  __shared__ float convL[4][12][64];
  __shared__ float valL[4][MAXNZ];
  __shared__ int   idxL[4][MAXNZ];

  int cnt = nnz[j];
  for (int s = lane; s < cnt; s += 64) {
    idxL[wv][s] = cidx[j * MAXNZ + s];
    valL[wv][s] = evals[(size_t)unit * MAXNZ + s];
  }
  {
    float v0 = lane < cnt        ? valL[wv][lane]      : -__builtin_inff();
    float v1 = (lane + 64) < cnt ? valL[wv][lane + 64] : -__builtin_inff();
    float mx = fmaxf(v0, v1);
    #pragma unroll
    for (int off = 32; off; off >>= 1) mx = fmaxf(mx, __shfl_xor(mx, off, 64));
    float e0 = lane < cnt        ? __expf(v0 - mx) : 0.f;
    float e1 = (lane + 64) < cnt ? __expf(v1 - mx) : 0.f;
    float ssum = wred_sum(e0 + e1);
    float inv = 1.0f / ssum;
    if (lane < cnt)        valL[wv][lane]      = e0 * inv;
    if ((lane + 64) < cnt) valL[wv][lane + 64] = e1 * inv;
  }

  float acc[12];
  #pragma unroll
  for (int t = 0; t < 12; ++t) acc[t] = 0.f;

  const float* xb = x + (size_t)b * TT * NN * FF + lane;
  for (int s = 0; s < cnt; ++s) {
    float v = valL[wv][s];
    const float* xk = xb + (size_t)idxL[wv][s] * FF;
    #pragma unroll
    for (int t = 0; t < 12; ++t)
      acc[t] = fmaf(v, xk[(size_t)t * NN * FF], acc[t]);
  }
  #pragma unroll
  for (int t = 0; t < 12; ++t) convL[wv][t][lane] = acc[t];

  float bs = bias[lane];
  float o[12];
  #pragma unroll
  for (int t = 0; t < 12; ++t) o[t] = bs;
  __syncthreads();

  #pragma unroll
  for (int ft = 0; ft < 4; ++ft) {
    float kc[16];
    #pragma unroll
    for (int i = 0; i < 16; ++i) kc[i] = K[(ft * 16 + i) * 64 + lane];
    #pragma unroll
    for (int t = 0; t < 12; ++t) {
      const float4* cv = (const float4*)&convL[wv][t][ft * 16];
      float4 c0 = cv[0], c1 = cv[1], c2 = cv[2], c3 = cv[3];
      float o_ = o[t];
      o_ = fmaf(c0.x, kc[0],  o_); o_ = fmaf(c0.y, kc[1],  o_);
      o_ = fmaf(c0.z, kc[2],  o_); o_ = fmaf(c0.w, kc[3],  o_);
      o_ = fmaf(c1.x, kc[4],  o_); o_ = fmaf(c1.y, kc[5],  o_);
      o_ = fmaf(c1.z, kc[6],  o_); o_ = fmaf(c1.w, kc[7],  o_);
      o_ = fmaf(c2.x, kc[8],  o_); o_ = fmaf(c2.y, kc[9],  o_);
      o_ = fmaf(c2.z, kc[10], o_); o_ = fmaf(c2.w, kc[11], o_);
      o_ = fmaf(c3.x, kc[12], o_); o_ = fmaf(c3.y, kc[13], o_);
      o_ = fmaf(c3.z, kc[14], o_); o_ = fmaf(c3.w, kc[15], o_);
      o[t] = o_;
    }
  }

  #pragma unroll
  for (int t = 0; t < 12; ++t)
    out[((size_t)(b * TT + t) * NN + j) * UU + lane] = o[t];
}

// ---------------------------------------------------------------------------
extern "C" void kernel_launch(void* const* d_in, const int* in_sizes, int n_in,
                              void* d_out, int out_size, void* d_ws, size_t ws_size,
                              hipStream_t stream)
{
  const float* x    = (const float*)d_in[0];  // (B,T,N,F)
  const float* A    = (const float*)d_in[1];  // (N,N)
  const float* W1   = (const float*)d_in[2];  // (T,1)
  const float* W2   = (const float*)d_in[3];  // (F,T)
  const float* W3   = (const float*)d_in[4];  // (F,1)
  const float* Ve   = (const float*)d_in[5];  // (N,N)
  const float* be   = (const float*)d_in[6];  // (N,N)
  const float* K    = (const float*)d_in[7];  // (F,U)
  const float* bias = (const float*)d_in[8];  // (U,)
  float* out = (float*)d_out;

  char* ws = (char*)d_ws;
  float* lhs   = (float*)ws + OF_LHS;
  float* rhsS  = (float*)ws + OF_RHS;
  float* beT   = (float*)ws + OF_BET;
  float* evals = (float*)ws + OF_EVALS;
  int*      nnz  = (int*)(ws + OB_NNZ);
  int*      cidx = (int*)(ws + OB_CIDX);
  int*      ccnt = (int*)(ws + OB_CCNT);
  unsigned* colj = (unsigned*)(ws + OB_COLJ);
  unsigned short* xT  = (unsigned short*)(ws + OB_XT);
  unsigned short* KF  = (unsigned short*)(ws + OB_KF);
  unsigned short* VeB = (unsigned short*)(ws + OB_VEB);
  unsigned short* ST  = (unsigned short*)(ws + OB_ST);

  const bool use_xt    = ws_size >= OB_KF + KF_BYTES;
  const bool use_veb   = ws_size >= OB_VEB + VEB_BYTES;
  const bool use_mfmaE = ws_size >= OB_ST + ST_BYTES;

  hipMemsetAsync(ccnt, 0, NN * sizeof(int), stream);

  // 1. lhs / rhs (+ transposed bf16 copy of x)
  k_lhs_rhs<<<dim3(BB * NN / 4), dim3(256), 0, stream>>>(
      x, W1, W2, W3, lhs, rhsS, use_xt ? xT : nullptr);
  // 2. transpose be (+ KF + VeB builds)
  k_transpose<<<dim3(NN * NN / 256 + 1 + (use_veb ? 32 : 0)), dim3(256), 0, stream>>>(
      be, beT, K, use_xt ? KF : nullptr, Ve, use_veb ? VeB : nullptr);
  // 3. row index lists
  k_build_idx<<<dim3(NN), dim3(64), 0, stream>>>(A, nnz, cidx);
  // 4. column lists
  k_build_col<<<dim3(NN), dim3(64), 0, stream>>>(nnz, cidx, ccnt, colj);
  // 5. product + sigmoid + masked E
  if (use_mfmaE && use_veb) {
    k_sigmoid2<<<dim3(BB, NN / 16), dim3(256), 0, stream>>>(lhs, rhsS, beT, ST);
    k_E_mfma<<<dim3(NN), dim3(256), 0, stream>>>(ST, VeB, ccnt, colj, evals);
  } else if (use_veb) {
    k_product_E6<<<dim3(BB, NN / 8), dim3(256), 0, stream>>>(lhs, rhsS, beT, VeB, ccnt, colj, evals);
  } else {
    k_product_E5<<<dim3(BB, NN / 8), dim3(256), 0, stream>>>(lhs, rhsS, beT, Ve, ccnt, colj, evals);
  }
  // 6. sparse conv + fused softmax + MFMA output GEMM
  if (use_xt)
    k_out12<<<dim3(BB * NN / 4), dim3(256), 0, stream>>>(xT, nnz, cidx, evals, KF, bias, out);
  else
    k_out3f<<<dim3(BB * NN / 4), dim3(256), 0, stream>>>(x, nnz, cidx, evals, K, bias, out);
}

// Round 22
// 179.430 us; speedup vs baseline: 1.2464x; 1.0116x over previous
//
#include <hip/hip_runtime.h>
#include <hip/hip_bf16.h>
#include <cstdint>

// Problem constants
constexpr int BB = 64;    // batch
constexpr int TT = 12;    // time
constexpr int NN = 512;   // nodes
constexpr int FF = 64;    // features
constexpr int UU = 64;    // units
constexpr int MAXNZ = 128;

// ---------------------------------------------------------------------------
// Workspace layout (bytes):
//   floats: lhs 0 / rhs 393216f / beT 786432f / evals 1048576f
//   ints:   nnz 20971520 / cidx 20973568 / ccnt 21235712 / colj 21237760
//   xT (B,N,T,F) bf16 : 21516288, 50331648 B
//   KF  : 71847936, 8192 B
//   VeB : 71856128, 524288 B
//   ST (B,N,N) bf16 [b][m][k] : 72380416, 33554432 B  -> ends 105934848
// ---------------------------------------------------------------------------
constexpr size_t OF_LHS   = 0;
constexpr size_t OF_RHS   = 393216;
constexpr size_t OF_BET   = 786432;
constexpr size_t OF_EVALS = 1048576;
constexpr size_t OB_NNZ   = 20971520;
constexpr size_t OB_CIDX  = 20973568;
constexpr size_t OB_CCNT  = 21235712;
constexpr size_t OB_COLJ  = 21237760;
constexpr size_t OB_XT    = 21516288;
constexpr size_t XT_BYTES = (size_t)BB * NN * TT * FF * 2;  // 50331648
constexpr size_t OB_KF    = 71847936;
constexpr size_t KF_BYTES = 8 * 64 * 8 * 2;                 // 8192
constexpr size_t OB_VEB   = 71856128;
constexpr size_t VEB_BYTES = (size_t)NN * NN * 2;           // 524288
constexpr size_t OB_ST    = 72380416;
constexpr size_t ST_BYTES = (size_t)BB * NN * NN * 2;       // 33554432

typedef __attribute__((ext_vector_type(8))) short bf16x8;   // 8 bf16 = 4 VGPRs
typedef __attribute__((ext_vector_type(4))) float f32x4;

__device__ __forceinline__ float wred_sum(float v) {
  #pragma unroll
  for (int off = 32; off; off >>= 1) v += __shfl_xor(v, off, 64);
  return v;
}

__device__ __forceinline__ float bflo(unsigned u) {
  return __uint_as_float(u << 16);
}
__device__ __forceinline__ float bfhi(unsigned u) {
  return __uint_as_float(u & 0xFFFF0000u);
}

// ---------------------------------------------------------------------------
// Kernel 1: lhs/rhs reductions; also writes xT[b][n][t][f] bf16
// ---------------------------------------------------------------------------
__global__ __launch_bounds__(256) void k_lhs_rhs(
    const float* __restrict__ x, const float* __restrict__ W1,
    const float* __restrict__ W2, const float* __restrict__ W3,
    float* __restrict__ lhs, float* __restrict__ rhsS,
    unsigned short* __restrict__ xT)   // may be null
{
  int unit = blockIdx.x * 4 + (threadIdx.x >> 6);   // b*512 + n
  int lane = threadIdx.x & 63;
  int b = unit >> 9, n = unit & 511;

  const float* xb = x + ((size_t)b * TT * NN + n) * FF + lane;
  float xv[12];
  #pragma unroll
  for (int t = 0; t < 12; ++t) xv[t] = xb[(size_t)t * NN * FF];

  if (xT) {
    unsigned short* xo = xT + (size_t)unit * (TT * FF) + lane;
    #pragma unroll
    for (int t = 0; t < 12; ++t) {
      __hip_bfloat16 h = __float2bfloat16(xv[t]);   // RTNE
      xo[t * FF] = *reinterpret_cast<unsigned short*>(&h);
    }
  }

  float r1 = 0.f;
  #pragma unroll
  for (int t = 0; t < 12; ++t) r1 += xv[t] * W1[t];

  float w3 = W3[lane];

  float myl = 0.f, myr = 0.f;
  #pragma unroll
  for (int t = 0; t < 12; ++t) {
    float a = r1 * W2[lane * 12 + t];
    float c = xv[t] * w3;
    a = wred_sum(a);
    c = wred_sum(c);
    if (lane == t) { myl = a; myr = c; }
  }
  if (lane < 12) {
    lhs[(size_t)unit * 12 + lane]  = myl;
    rhsS[(size_t)unit * 12 + lane] = myr;
  }
}

// ---------------------------------------------------------------------------
// Kernel 2: beT[m,k] = be[k,m]; block 1024 builds KF; blocks 1025+ build VeB.
// ---------------------------------------------------------------------------
__global__ __launch_bounds__(256) void k_transpose(
    const float* __restrict__ be, float* __restrict__ beT,
    const float* __restrict__ K, unsigned short* __restrict__ KF,
    const float* __restrict__ Ve, unsigned short* __restrict__ VeB)
{
  int bid = blockIdx.x;
  if (bid < NN * NN / 256) {
    int i = bid * 256 + threadIdx.x;  // 262144 total
    int k = i >> 9, m = i & 511;
    beT[m * 512 + k] = be[i];
    return;
  }
  if (bid == NN * NN / 256) {
    if (KF) {
      for (int idx = threadIdx.x; idx < 512; idx += 256) {
        int frag = idx >> 6, l = idx & 63;
        int kk = frag >> 2, nt = frag & 3;
        int u = nt * 16 + (l & 15);
        unsigned short* dst = KF + (size_t)idx * 8;
        for (int e = 0; e < 8; ++e) {
          int f = kk * 32 + (l >> 4) * 8 + e;
          __hip_bfloat16 h = __float2bfloat16(K[f * 64 + u]);
          dst[e] = *reinterpret_cast<unsigned short*>(&h);
        }
      }
    }
    return;
  }
  if (VeB) {
    int b2 = bid - (NN * NN / 256 + 1);   // 0..31
    #pragma unroll
    for (int i = 0; i < 32; ++i) {
      int idx = b2 * 8192 + i * 256 + threadIdx.x;
      __hip_bfloat16 h = __float2bfloat16(Ve[idx]);
      VeB[idx] = *reinterpret_cast<unsigned short*>(&h);
    }
  }
}

// ---------------------------------------------------------------------------
// Kernel 3: row-wise compaction of mask A (deterministic, ordered by m)
// ---------------------------------------------------------------------------
__global__ void k_build_idx(const float* __restrict__ A,
                            int* __restrict__ nnz, int* __restrict__ cidx)
{
  int j = blockIdx.x;
  int lane = threadIdx.x;  // 64 threads
  unsigned long long lt = (1ull << lane) - 1ull;
  int base = 0;
  for (int c = 0; c < 8; ++c) {
    int m = c * 64 + lane;
    bool p = A[(size_t)j * 512 + m] > 0.5f;
    unsigned long long mask = __ballot(p);
    int pos = base + __popcll(mask & lt);
    if (p && pos < MAXNZ) cidx[j * MAXNZ + pos] = m;
    base += __popcll(mask);
  }
  if (lane == 0) nnz[j] = base > MAXNZ ? MAXNZ : base;
}

// ---------------------------------------------------------------------------
// Kernel 4: column lists
// ---------------------------------------------------------------------------
__global__ void k_build_col(const int* __restrict__ nnz, const int* __restrict__ cidx,
                            int* __restrict__ ccnt, unsigned* __restrict__ colj)
{
  int j = blockIdx.x;
  int lane = threadIdx.x;
  int cnt = nnz[j];
  for (int s = lane; s < cnt; s += 64) {
    int m = cidx[j * MAXNZ + s];
    int pos = atomicAdd(&ccnt[m], 1);
    if (pos < MAXNZ) colj[m * MAXNZ + pos] = (unsigned)j | ((unsigned)s << 16);
  }
}

// ---------------------------------------------------------------------------
// Kernel 5a (MFMA path): streaming sigmoid -> ST[b][m][k] bf16.
//   Register lhs (E5-proven), no sL tile, coalesced 2B stores.
// ---------------------------------------------------------------------------
__global__ __launch_bounds__(256) void k_sigmoid2(
    const float* __restrict__ lhs, const float* __restrict__ rhsS,
    const float* __restrict__ beT, unsigned short* __restrict__ ST)
{
  int b  = blockIdx.x;   // 0..63
  int mc = blockIdx.y;   // 0..31 (16 m's)

  __shared__ float rh[16 * 12];
  int tid = threadIdx.x;

  float l0[12], l1[12];
  {
    const float* p0 = lhs + ((size_t)b * 512 + tid) * 12;
    const float* p1 = p0 + 256 * 12;
    #pragma unroll
    for (int t = 0; t < 12; ++t) { l0[t] = p0[t]; l1[t] = p1[t]; }
  }
  if (tid < 192) rh[tid] = rhsS[((size_t)b * 512 + mc * 16) * 12 + tid];
  __syncthreads();

  #pragma unroll 4
  for (int mm = 0; mm < 16; ++mm) {
    int m = mc * 16 + mm;
    float q0 = beT[m * 512 + tid];
    float q1 = beT[m * 512 + tid + 256];
    const float* rw = &rh[mm * 12];
    #pragma unroll
    for (int t = 0; t < 12; ++t) {
      q0 = fmaf(l0[t], rw[t], q0);
      q1 = fmaf(l1[t], rw[t], q1);
    }
    float s0 = 1.0f / (1.0f + __expf(-q0));
    float s1 = 1.0f / (1.0f + __expf(-q1));
    __hip_bfloat16 h0 = __float2bfloat16(s0);
    __hip_bfloat16 h1 = __float2bfloat16(s1);
    unsigned short* dst = ST + ((size_t)(b * NN + m)) * NN;
    dst[tid]       = *reinterpret_cast<unsigned short*>(&h0);
    dst[tid + 256] = *reinterpret_cast<unsigned short*>(&h1);
  }
}

// ---------------------------------------------------------------------------
// Kernel 5b (MFMA path): E[entries(m), b] = Ve[entries,:] @ S[:,m,b].
//   Block = column m (512 blocks, 4 waves; wave w owns b-tile w*16..+16).
//   B-frags: 16 k-steps of S from ST (dwordx4, register-resident, 64 VGPR).
//   A: 32 Ve entry-rows gathered to LDS VeL[32][520] (pad -> 2-way banks).
//   2 j-tiles x 16 k-steps of mfma_f32_16x16x32_bf16 per wave per chunk.
//   A/B share k-map (l>>4)*8+e (k-permutation invariance, as k_out12).
//   D: col=lane&15 = b_local, row=(lane>>4)*4+reg = entry (HW-verified map);
//   scatter dword writes to evals[b][j][slot].
// ---------------------------------------------------------------------------
__global__ __launch_bounds__(256) void k_E_mfma(
    const unsigned short* __restrict__ ST, const unsigned short* __restrict__ VeB,
    const int* __restrict__ ccnt, const unsigned* __restrict__ colj,
    float* __restrict__ evals)
{
  int m = blockIdx.x;            // 0..511
  int tid = threadIdx.x;
  int wv = tid >> 6, lane = tid & 63;
  int arow = lane & 15, kgrp = lane >> 4;

  __shared__ unsigned short VeL[32][520];   // 33.3 KB (row stride 1040 B)
  __shared__ unsigned entL[MAXNZ];

  int cnt = ccnt[m];
  if (cnt > MAXNZ) cnt = MAXNZ;
  for (int e = tid; e < cnt; e += 256) entL[e] = colj[m * MAXNZ + e];

  // B-fragments (register-resident): lane holds S[k=kgrp*8+kk*32 ..+8][b]
  bf16x8 bfrag[16];
  {
    const unsigned short* sb =
        ST + ((size_t)((wv * 16 + arow) * NN + m)) * NN + kgrp * 8;
    #pragma unroll
    for (int kk = 0; kk < 16; ++kk)
      bfrag[kk] = *reinterpret_cast<const bf16x8*>(sb + kk * 32);
  }

  for (int c0 = 0; c0 < cnt; c0 += 32) {
    __syncthreads();   // entL ready (1st iter); VeL consumed (later iters)
    // stage 32 Ve rows (zero-pad past cnt); 8 threads/row, 64B-interleaved
    {
      int r = tid >> 3, seg = tid & 7;
      int e = c0 + r;
      uint2* dst = reinterpret_cast<uint2*>(&VeL[r][0]);
      if (e < cnt) {
        unsigned jrow = entL[e] & 0xffffu;
        const uint2* src = reinterpret_cast<const uint2*>(VeB + (size_t)jrow * 512);
        #pragma unroll
        for (int i = 0; i < 16; ++i) dst[seg + 8 * i] = src[seg + 8 * i];
      } else {
        uint2 z = make_uint2(0u, 0u);
        #pragma unroll
        for (int i = 0; i < 16; ++i) dst[seg + 8 * i] = z;
      }
    }
    __syncthreads();

    int b = wv * 16 + arow;
    #pragma unroll
    for (int jt = 0; jt < 2; ++jt) {
      f32x4 acc = {0.f, 0.f, 0.f, 0.f};
      #pragma unroll
      for (int kk = 0; kk < 16; ++kk) {
        bf16x8 af = *reinterpret_cast<const bf16x8*>(
            &VeL[jt * 16 + arow][kgrp * 8 + kk * 32]);
        acc = __builtin_amdgcn_mfma_f32_16x16x32_bf16(af, bfrag[kk], acc, 0, 0, 0);
      }
      #pragma unroll
      for (int r = 0; r < 4; ++r) {
        int e = c0 + jt * 16 + kgrp * 4 + r;
        if (e < cnt) {
          unsigned pk = entL[e];
          int j = pk & 0xffff, slot = (int)(pk >> 16);
          evals[((size_t)b * 512 + j) * MAXNZ + slot] = acc[r];
        }
      }
    }
  }
}

// ---------------------------------------------------------------------------
// Kernel 5 fallback (v6): E5 structure, bf16 Ve reads (R20-measured 84us)
// ---------------------------------------------------------------------------
__global__ __launch_bounds__(256) void k_product_E6(
    const float* __restrict__ lhs, const float* __restrict__ rhsS,
    const float* __restrict__ beT, const unsigned short* __restrict__ VeB,
    const int* __restrict__ ccnt, const unsigned* __restrict__ colj,
    float* __restrict__ evals)
{
  int b  = blockIdx.x;
  int mc = blockIdx.y;

  __shared__ __align__(16) float sL[8][512];
  __shared__ float rh[8 * 12];

  int tid = threadIdx.x;
  int wave = tid >> 6, lane = tid & 63;
  int grp = lane >> 4, lg = lane & 15;

  float l0[12], l1[12];
  {
    const float* p0 = lhs + ((size_t)b * 512 + tid) * 12;
    const float* p1 = p0 + 256 * 12;
    #pragma unroll
    for (int t = 0; t < 12; ++t) { l0[t] = p0[t]; l1[t] = p1[t]; }
  }
  if (tid < 96) rh[tid] = rhsS[((size_t)b * 512 + mc * 8) * 12 + tid];
  __syncthreads();

  #pragma unroll
  for (int mm = 0; mm < 8; ++mm) {
    int m = mc * 8 + mm;
    float q0 = beT[m * 512 + tid];
    float q1 = beT[m * 512 + tid + 256];
    const float* rw = &rh[mm * 12];
    #pragma unroll
    for (int t = 0; t < 12; ++t) {
      q0 = fmaf(l0[t], rw[t], q0);
      q1 = fmaf(l1[t], rw[t], q1);
    }
    sL[mm][tid]       = 1.0f / (1.0f + __expf(-q0));
    sL[mm][tid + 256] = 1.0f / (1.0f + __expf(-q1));
  }
  __syncthreads();

  for (int cc = 0; cc < 2; ++cc) {
    int mm = wave + cc * 4;
    int m = mc * 8 + mm;
    int cnt = ccnt[m];
    if (cnt > MAXNZ) cnt = MAXNZ;
    const float4* sw4 = (const float4*)sL[mm];
    const unsigned* cj = colj + m * MAXNZ;

    int e0 = grp;
    for (; e0 + 4 < cnt; e0 += 8) {
      unsigned pk0 = cj[e0], pk1 = cj[e0 + 4];
      int j0 = pk0 & 0xffff, s0 = (int)(pk0 >> 16);
      int j1 = pk1 & 0xffff, s1 = (int)(pk1 >> 16);
      const uint2* va = (const uint2*)(VeB + (size_t)j0 * 512);
      const uint2* vb = (const uint2*)(VeB + (size_t)j1 * 512);
      float a = 0.f, c = 0.f;
      #pragma unroll
      for (int i = 0; i < 8; ++i) {
        float4 s4 = sw4[lg + 16 * i];
        uint2  u0 = va[lg + 16 * i];
        uint2  u1 = vb[lg + 16 * i];
        a = fmaf(bflo(u0.x), s4.x, a); a = fmaf(bfhi(u0.x), s4.y, a);
        a = fmaf(bflo(u0.y), s4.z, a); a = fmaf(bfhi(u0.y), s4.w, a);
        c = fmaf(bflo(u1.x), s4.x, c); c = fmaf(bfhi(u1.x), s4.y, c);
        c = fmaf(bflo(u1.y), s4.z, c); c = fmaf(bfhi(u1.y), s4.w, c);
      }
      #pragma unroll
      for (int off = 8; off; off >>= 1) {
        a += __shfl_xor(a, off, 64);
        c += __shfl_xor(c, off, 64);
      }
      if (lg == 0) {
        evals[((size_t)b * 512 + j0) * MAXNZ + s0] = a;
        evals[((size_t)b * 512 + j1) * MAXNZ + s1] = c;
      }
    }
    if (e0 < cnt) {
      unsigned pk0 = cj[e0];
      int j0 = pk0 & 0xffff, s0 = (int)(pk0 >> 16);
      const uint2* va = (const uint2*)(VeB + (size_t)j0 * 512);
      float a = 0.f;
      #pragma unroll
      for (int i = 0; i < 8; ++i) {
        float4 s4 = sw4[lg + 16 * i];
        uint2  u0 = va[lg + 16 * i];
        a = fmaf(bflo(u0.x), s4.x, a); a = fmaf(bfhi(u0.x), s4.y, a);
        a = fmaf(bflo(u0.y), s4.z, a); a = fmaf(bfhi(u0.y), s4.w, a);
      }
      #pragma unroll
      for (int off = 8; off; off >>= 1) a += __shfl_xor(a, off, 64);
      if (lg == 0) evals[((size_t)b * 512 + j0) * MAXNZ + s0] = a;
    }
  }
}

// ---------------------------------------------------------------------------
// Kernel 5 fallback (fp32 Ve, E5 structure) — if ws too small for VeB
// ---------------------------------------------------------------------------
__global__ __launch_bounds__(256) void k_product_E5(
    const float* __restrict__ lhs, const float* __restrict__ rhsS,
    const float* __restrict__ beT, const float* __restrict__ Ve,
    const int* __restrict__ ccnt, const unsigned* __restrict__ colj,
    float* __restrict__ evals)
{
  int b  = blockIdx.x;
  int mc = blockIdx.y;

  __shared__ __align__(16) float sL[8][512];
  __shared__ float rh[8 * 12];

  int tid = threadIdx.x;
  int wave = tid >> 6, lane = tid & 63;
  int grp = lane >> 4, lg = lane & 15;

  float l0[12], l1[12];
  {
    const float* p0 = lhs + ((size_t)b * 512 + tid) * 12;
    const float* p1 = p0 + 256 * 12;
    #pragma unroll
    for (int t = 0; t < 12; ++t) { l0[t] = p0[t]; l1[t] = p1[t]; }
  }
  if (tid < 96) rh[tid] = rhsS[((size_t)b * 512 + mc * 8) * 12 + tid];
  __syncthreads();

  #pragma unroll
  for (int mm = 0; mm < 8; ++mm) {
    int m = mc * 8 + mm;
    float q0 = beT[m * 512 + tid];
    float q1 = beT[m * 512 + tid + 256];
    const float* rw = &rh[mm * 12];
    #pragma unroll
    for (int t = 0; t < 12; ++t) {
      q0 = fmaf(l0[t], rw[t], q0);
      q1 = fmaf(l1[t], rw[t], q1);
    }
    sL[mm][tid]       = 1.0f / (1.0f + __expf(-q0));
    sL[mm][tid + 256] = 1.0f / (1.0f + __expf(-q1));
  }
  __syncthreads();

  for (int cc = 0; cc < 2; ++cc) {
    int mm = wave + cc * 4;
    int m = mc * 8 + mm;
    int cnt = ccnt[m];
    if (cnt > MAXNZ) cnt = MAXNZ;
    const float4* sw4 = (const float4*)sL[mm];
    const unsigned* cj = colj + m * MAXNZ;

    int e0 = grp;
    for (; e0 + 4 < cnt; e0 += 8) {
      unsigned pk0 = cj[e0], pk1 = cj[e0 + 4];
      int j0 = pk0 & 0xffff, s0 = (int)(pk0 >> 16);
      int j1 = pk1 & 0xffff, s1 = (int)(pk1 >> 16);
      const float4* va = (const float4*)(Ve + (size_t)j0 * 512);
      const float4* vb = (const float4*)(Ve + (size_t)j1 * 512);
      float a = 0.f, c = 0.f;
      #pragma unroll
      for (int i = 0; i < 8; ++i) {
        float4 s4 = sw4[lg + 16 * i];
        float4 v4 = va[lg + 16 * i];
        float4 w4 = vb[lg + 16 * i];
        a = fmaf(v4.x, s4.x, a); a = fmaf(v4.y, s4.y, a);
        a = fmaf(v4.z, s4.z, a); a = fmaf(v4.w, s4.w, a);
        c = fmaf(w4.x, s4.x, c); c = fmaf(w4.y, s4.y, c);
        c = fmaf(w4.z, s4.z, c); c = fmaf(w4.w, s4.w, c);
      }
      #pragma unroll
      for (int off = 8; off; off >>= 1) {
        a += __shfl_xor(a, off, 64);
        c += __shfl_xor(c, off, 64);
      }
      if (lg == 0) {
        evals[((size_t)b * 512 + j0) * MAXNZ + s0] = a;
        evals[((size_t)b * 512 + j1) * MAXNZ + s1] = c;
      }
    }
    if (e0 < cnt) {
      unsigned pk0 = cj[e0];
      int j0 = pk0 & 0xffff, s0 = (int)(pk0 >> 16);
      const float4* va = (const float4*)(Ve + (size_t)j0 * 512);
      float a = 0.f;
      #pragma unroll
      for (int i = 0; i < 8; ++i) {
        float4 s4 = sw4[lg + 16 * i];
        float4 v4 = va[lg + 16 * i];
        a = fmaf(v4.x, s4.x, a); a = fmaf(v4.y, s4.y, a);
        a = fmaf(v4.z, s4.z, a); a = fmaf(v4.w, s4.w, a);
      }
      #pragma unroll
      for (int off = 8; off; off >>= 1) a += __shfl_xor(a, off, 64);
      if (lg == 0) evals[((size_t)b * 512 + j0) * MAXNZ + s0] = a;
    }
  }
}

// ---------------------------------------------------------------------------
// Kernel 6 (v12): wave per (b,j). Phase A = xT bf16 gather + fused softmax.
//   Phase B = MFMA (8x mfma_f32_16x16x32_bf16).
// XCD swizzle: grid = 8192, sbid = (bid&7)*1024 + (bid>>3) bijective.
// ---------------------------------------------------------------------------
__global__ __launch_bounds__(256) void k_out12(
    const unsigned short* __restrict__ xT,
    const int* __restrict__ nnz, const int* __restrict__ cidx,
    const float* __restrict__ evals,
    const unsigned short* __restrict__ KF, const float* __restrict__ bias,
    float* __restrict__ out)
{
  int tid = threadIdx.x;
  int wv = tid >> 6, lane = tid & 63;
  int bid = blockIdx.x;
  int sbid = (bid & 7) * 1024 + (bid >> 3);  // bijective on [0,8192)
  int unit = sbid * 4 + wv;                  // b*512 + j
  int b = unit >> 9, j = unit & 511;

  __shared__ unsigned short convB[4][16][80];  // bf16, row stride 160 B
  __shared__ float valL[4][MAXNZ];
  __shared__ int   idxL[4][MAXNZ];

  int cnt = nnz[j];
  for (int s = lane; s < cnt; s += 64) {
    idxL[wv][s] = cidx[j * MAXNZ + s];
    valL[wv][s] = evals[(size_t)unit * MAXNZ + s];
  }
  // ---- fused masked softmax over this wave's slots (wave-local) ----
  {
    float v0 = lane < cnt        ? valL[wv][lane]      : -__builtin_inff();
    float v1 = (lane + 64) < cnt ? valL[wv][lane + 64] : -__builtin_inff();
    float mx = fmaxf(v0, v1);
    #pragma unroll
    for (int off = 32; off; off >>= 1) mx = fmaxf(mx, __shfl_xor(mx, off, 64));
    float e0 = lane < cnt        ? __expf(v0 - mx) : 0.f;
    float e1 = (lane + 64) < cnt ? __expf(v1 - mx) : 0.f;
    float ssum = wred_sum(e0 + e1);
    float inv = 1.0f / ssum;
    if (lane < cnt)        valL[wv][lane]      = e0 * inv;
    if ((lane + 64) < cnt) valL[wv][lane + 64] = e1 * inv;
  }

  // ---- phase A: bf16 gather from xT (contiguous, imm-offset) ----
  float2 acc[6];
  #pragma unroll
  for (int i = 0; i < 6; ++i) acc[i] = make_float2(0.f, 0.f);

  const unsigned* xb = reinterpret_cast<const unsigned*>(
      xT + (size_t)b * NN * (TT * FF));

  int s = 0;
  for (; s + 1 < cnt; s += 2) {
    int   k0 = idxL[wv][s],     k1 = idxL[wv][s + 1];
    float v0 = valL[wv][s],     v1 = valL[wv][s + 1];
    const unsigned* p0 = xb + k0 * 384 + lane;
    const unsigned* p1 = xb + k1 * 384 + lane;
    unsigned a0 = p0[0],   a1 = p0[64],  a2 = p0[128],
             a3 = p0[192], a4 = p0[256], a5 = p0[320];
    unsigned c0 = p1[0],   c1 = p1[64],  c2 = p1[128],
             c3 = p1[192], c4 = p1[256], c5 = p1[320];
    acc[0].x = fmaf(v0, bflo(a0), acc[0].x); acc[0].y = fmaf(v0, bfhi(a0), acc[0].y);
    acc[1].x = fmaf(v0, bflo(a1), acc[1].x); acc[1].y = fmaf(v0, bfhi(a1), acc[1].y);
    acc[2].x = fmaf(v0, bflo(a2), acc[2].x); acc[2].y = fmaf(v0, bfhi(a2), acc[2].y);
    acc[3].x = fmaf(v0, bflo(a3), acc[3].x); acc[3].y = fmaf(v0, bfhi(a3), acc[3].y);
    acc[4].x = fmaf(v0, bflo(a4), acc[4].x); acc[4].y = fmaf(v0, bfhi(a4), acc[4].y);
    acc[5].x = fmaf(v0, bflo(a5), acc[5].x); acc[5].y = fmaf(v0, bfhi(a5), acc[5].y);
    acc[0].x = fmaf(v1, bflo(c0), acc[0].x); acc[0].y = fmaf(v1, bfhi(c0), acc[0].y);
    acc[1].x = fmaf(v1, bflo(c1), acc[1].x); acc[1].y = fmaf(v1, bfhi(c1), acc[1].y);
    acc[2].x = fmaf(v1, bflo(c2), acc[2].x); acc[2].y = fmaf(v1, bfhi(c2), acc[2].y);
    acc[3].x = fmaf(v1, bflo(c3), acc[3].x); acc[3].y = fmaf(v1, bfhi(c3), acc[3].y);
    acc[4].x = fmaf(v1, bflo(c4), acc[4].x); acc[4].y = fmaf(v1, bfhi(c4), acc[4].y);
    acc[5].x = fmaf(v1, bflo(c5), acc[5].x); acc[5].y = fmaf(v1, bfhi(c5), acc[5].y);
  }
  if (s < cnt) {
    int   k0 = idxL[wv][s];
    float v0 = valL[wv][s];
    const unsigned* p0 = xb + k0 * 384 + lane;
    unsigned a0 = p0[0],   a1 = p0[64],  a2 = p0[128],
             a3 = p0[192], a4 = p0[256], a5 = p0[320];
    acc[0].x = fmaf(v0, bflo(a0), acc[0].x); acc[0].y = fmaf(v0, bfhi(a0), acc[0].y);
    acc[1].x = fmaf(v0, bflo(a1), acc[1].x); acc[1].y = fmaf(v0, bfhi(a1), acc[1].y);
    acc[2].x = fmaf(v0, bflo(a2), acc[2].x); acc[2].y = fmaf(v0, bfhi(a2), acc[2].y);
    acc[3].x = fmaf(v0, bflo(a3), acc[3].x); acc[3].y = fmaf(v0, bfhi(a3), acc[3].y);
    acc[4].x = fmaf(v0, bflo(a4), acc[4].x); acc[4].y = fmaf(v0, bfhi(a4), acc[4].y);
    acc[5].x = fmaf(v0, bflo(a5), acc[5].x); acc[5].y = fmaf(v0, bfhi(a5), acc[5].y);
  }

  // ---- stage conv to LDS as bf16 (acc[i] -> t = 2i+half, f = 2fl,2fl+1) ----
  int half = lane >> 5, fl = lane & 31;
  {
    unsigned short* cb = &convB[wv][0][0];
    #pragma unroll
    for (int i = 0; i < 6; ++i) {
      int t = 2 * i + half;
      __hip_bfloat16 hx = __float2bfloat16(acc[i].x);
      __hip_bfloat16 hy = __float2bfloat16(acc[i].y);
      unsigned pkd = (unsigned)*reinterpret_cast<unsigned short*>(&hx)
                   | ((unsigned)*reinterpret_cast<unsigned short*>(&hy) << 16);
      *reinterpret_cast<unsigned*>(&cb[t * 80 + fl * 2]) = pkd;
    }
  }

  // ---- phase B: 8x MFMA ----
  int arow = lane & 15, agrp = lane >> 4;
  bf16x8 afrag0 = *reinterpret_cast<const bf16x8*>(&convB[wv][arow][agrp * 8]);
  bf16x8 afrag1 = *reinterpret_cast<const bf16x8*>(&convB[wv][arow][32 + agrp * 8]);
  const bf16x8* kf = reinterpret_cast<const bf16x8*>(KF);

  #pragma unroll
  for (int nt = 0; nt < 4; ++nt) {
    f32x4 accT = {0.f, 0.f, 0.f, 0.f};
    accT = __builtin_amdgcn_mfma_f32_16x16x32_bf16(afrag0, kf[(0 * 4 + nt) * 64 + lane], accT, 0, 0, 0);
    accT = __builtin_amdgcn_mfma_f32_16x16x32_bf16(afrag1, kf[(1 * 4 + nt) * 64 + lane], accT, 0, 0, 0);
    int u = nt * 16 + arow;
    float bb = bias[u];
    #pragma unroll
    for (int r = 0; r < 4; ++r) {
      int t = agrp * 4 + r;   // D row = (lane>>4)*4 + reg (HW-verified)
      if (t < 12)
        out[((size_t)(b * TT + t) * NN + j) * UU + u] = accT[r] + bb;
    }
  }
}

// ---------------------------------------------------------------------------
// Kernel 6 fallback (fp32 scalar gather + fused softmax + fmaf phase B)
// ---------------------------------------------------------------------------
__global__ __launch_bounds__(256) void k_out3f(
    const float* __restrict__ x,
    const int* __restrict__ nnz, const int* __restrict__ cidx,
    const float* __restrict__ evals,
    const float* __restrict__ K, const float* __restrict__ bias,
    float* __restrict__ out)
{
  int wv = threadIdx.x >> 6, lane = threadIdx.x & 63;
  int bid = blockIdx.x;
  int sbid = (bid & 7) * 1024 + (bid >> 3);
  int unit = sbid * 4 + wv;
  int b = unit >> 9, j = unit & 511;

  __shared__ float convL[4][12][64];
  __shared__ float valL[4][MAXNZ];
  __shared__ int   idxL[4][MAXNZ];

  int cnt = nnz[j];
  for (int s = lane; s < cnt; s += 64) {
    idxL[wv][s] = cidx[j * MAXNZ + s];
    valL[wv][s] = evals[(size_t)unit * MAXNZ + s];
  }
  {
    float v0 = lane < cnt        ? valL[wv][lane]      : -__builtin_inff();
    float v1 = (lane + 64) < cnt ? valL[wv][lane + 64] : -__builtin_inff();
    float mx = fmaxf(v0, v1);
    #pragma unroll
    for (int off = 32; off; off >>= 1) mx = fmaxf(mx, __shfl_xor(mx, off, 64));
    float e0 = lane < cnt        ? __expf(v0 - mx) : 0.f;
    float e1 = (lane + 64) < cnt ? __expf(v1 - mx) : 0.f;
    float ssum = wred_sum(e0 + e1);
    float inv = 1.0f / ssum;
    if (lane < cnt)        valL[wv][lane]      = e0 * inv;
    if ((lane + 64) < cnt) valL[wv][lane + 64] = e1 * inv;
  }

  float acc[12];
  #pragma unroll
  for (int t = 0; t < 12; ++t) acc[t] = 0.f;

  const float* xb = x + (size_t)b * TT * NN * FF + lane;
  for (int s = 0; s < cnt; ++s) {
    float v = valL[wv][s];
    const float* xk = xb + (size_t)idxL[wv][s] * FF;
    #pragma unroll
    for (int t = 0; t < 12; ++t)
      acc[t] = fmaf(v, xk[(size_t)t * NN * FF], acc[t]);
  }
  #pragma unroll
  for (int t = 0; t < 12; ++t) convL[wv][t][lane] = acc[t];

  float bs = bias[lane];
  float o[12];
  #pragma unroll
  for (int t = 0; t < 12; ++t) o[t] = bs;
  __syncthreads();

  #pragma unroll
  for (int ft = 0; ft < 4; ++ft) {
    float kc[16];
    #pragma unroll
    for (int i = 0; i < 16; ++i) kc[i] = K[(ft * 16 + i) * 64 + lane];
    #pragma unroll
    for (int t = 0; t < 12; ++t) {
      const float4* cv = (const float4*)&convL[wv][t][ft * 16];
      float4 c0 = cv[0], c1 = cv[1], c2 = cv[2], c3 = cv[3];
      float o_ = o[t];
      o_ = fmaf(c0.x, kc[0],  o_); o_ = fmaf(c0.y, kc[1],  o_);
      o_ = fmaf(c0.z, kc[2],  o_); o_ = fmaf(c0.w, kc[3],  o_);
      o_ = fmaf(c1.x, kc[4],  o_); o_ = fmaf(c1.y, kc[5],  o_);
      o_ = fmaf(c1.z, kc[6],  o_); o_ = fmaf(c1.w, kc[7],  o_);
      o_ = fmaf(c2.x, kc[8],  o_); o_ = fmaf(c2.y, kc[9],  o_);
      o_ = fmaf(c2.z, kc[10], o_); o_ = fmaf(c2.w, kc[11], o_);
      o_ = fmaf(c3.x, kc[12], o_); o_ = fmaf(c3.y, kc[13], o_);
      o_ = fmaf(c3.z, kc[14], o_); o_ = fmaf(c3.w, kc[15], o_);
      o[t] = o_;
    }
  }

  #pragma unroll
  for (int t = 0; t < 12; ++t)
    out[((size_t)(b * TT + t) * NN + j) * UU + lane] = o[t];
}

// ---------------------------------------------------------------------------
extern "C" void kernel_launch(void* const* d_in, const int* in_sizes, int n_in,
                              void* d_out, int out_size, void* d_ws, size_t ws_size,
                              hipStream_t stream)
{
  const float* x    = (const float*)d_in[0];  // (B,T,N,F)
  const float* A    = (const float*)d_in[1];  // (N,N)
  const float* W1   = (const float*)d_in[2];  // (T,1)
  const float* W2   = (const float*)d_in[3];  // (F,T)
  const float* W3   = (const float*)d_in[4];  // (F,1)
  const float* Ve   = (const float*)d_in[5];  // (N,N)
  const float* be   = (const float*)d_in[6];  // (N,N)
  const float* K    = (const float*)d_in[7];  // (F,U)
  const float* bias = (const float*)d_in[8];  // (U,)
  float* out = (float*)d_out;

  char* ws = (char*)d_ws;
  float* lhs   = (float*)ws + OF_LHS;
  float* rhsS  = (float*)ws + OF_RHS;
  float* beT   = (float*)ws + OF_BET;
  float* evals = (float*)ws + OF_EVALS;
  int*      nnz  = (int*)(ws + OB_NNZ);
  int*      cidx = (int*)(ws + OB_CIDX);
  int*      ccnt = (int*)(ws + OB_CCNT);
  unsigned* colj = (unsigned*)(ws + OB_COLJ);
  unsigned short* xT  = (unsigned short*)(ws + OB_XT);
  unsigned short* KF  = (unsigned short*)(ws + OB_KF);
  unsigned short* VeB = (unsigned short*)(ws + OB_VEB);
  unsigned short* ST  = (unsigned short*)(ws + OB_ST);

  const bool use_xt    = ws_size >= OB_KF + KF_BYTES;
  const bool use_veb   = ws_size >= OB_VEB + VEB_BYTES;
  const bool use_mfmaE = ws_size >= OB_ST + ST_BYTES;

  hipMemsetAsync(ccnt, 0, NN * sizeof(int), stream);

  // 1. lhs / rhs (+ transposed bf16 copy of x)
  k_lhs_rhs<<<dim3(BB * NN / 4), dim3(256), 0, stream>>>(
      x, W1, W2, W3, lhs, rhsS, use_xt ? xT : nullptr);
  // 2. transpose be (+ KF + VeB builds)
  k_transpose<<<dim3(NN * NN / 256 + 1 + (use_veb ? 32 : 0)), dim3(256), 0, stream>>>(
      be, beT, K, use_xt ? KF : nullptr, Ve, use_veb ? VeB : nullptr);
  // 3. row index lists
  k_build_idx<<<dim3(NN), dim3(64), 0, stream>>>(A, nnz, cidx);
  // 4. column lists
  k_build_col<<<dim3(NN), dim3(64), 0, stream>>>(nnz, cidx, ccnt, colj);
  // 5. product + sigmoid + masked E
  if (use_mfmaE && use_veb) {
    k_sigmoid2<<<dim3(BB, NN / 16), dim3(256), 0, stream>>>(lhs, rhsS, beT, ST);
    k_E_mfma<<<dim3(NN), dim3(256), 0, stream>>>(ST, VeB, ccnt, colj, evals);
  } else if (use_veb) {
    k_product_E6<<<dim3(BB, NN / 8), dim3(256), 0, stream>>>(lhs, rhsS, beT, VeB, ccnt, colj, evals);
  } else {
    k_product_E5<<<dim3(BB, NN / 8), dim3(256), 0, stream>>>(lhs, rhsS, beT, Ve, ccnt, colj, evals);
  }
  // 6. sparse conv + fused softmax + MFMA output GEMM
  if (use_xt)
    k_out12<<<dim3(BB * NN / 4), dim3(256), 0, stream>>>(xT, nnz, cidx, evals, KF, bias, out);
  else
    k_out3f<<<dim3(BB * NN / 4), dim3(256), 0, stream>>>(x, nnz, cidx, evals, K, bias, out);
}